// Round 6
// baseline (499.434 us; speedup 1.0000x reference)
//
#include <hip/hip_runtime.h>
#include <hip/hip_bf16.h>
#include <stdint.h>

#define T_SEQ 8192
#define BB    4
#define DH    512
#define DIN   512
#define M_TOT (BB*T_SEQ)          // 32768
#define BM    128
#define BCH   128                 // channels per block -> 3*BCH = 384 N-rows in LDS
#define BK    64
#define NKT   24                  // K_aug = 1536 = 24 * 64 (A=[hi,lo,hi] x B=[hi,hi,lo])
#define KS    1024                // stored ushorts per row: [hi(512) | lo(512)]
#define CHUNK_L 128
#define NCHUNK  64
#define NCH_TOT (BB*DH)           // 2048

#define XB_BLOCKS 8192            // xaug part of merged build kernel
#define BM_BLOCKS 384             // bmat part

typedef __attribute__((ext_vector_type(4))) float f32x4;
typedef __attribute__((ext_vector_type(8))) short bf16x8;

__device__ __forceinline__ unsigned short f2bf_rne(float x){
  unsigned u = __float_as_uint(x);
  return (unsigned short)((u + 0x7FFFu + ((u >> 16) & 1u)) >> 16);
}
__device__ __forceinline__ float bf2f(unsigned short h){
  return __uint_as_float(((unsigned)h) << 16);
}
__device__ __forceinline__ void gld16(const void* g, void* l){
  __builtin_amdgcn_global_load_lds((const __attribute__((address_space(1))) unsigned*)g,
                                   (__attribute__((address_space(3))) unsigned*)l, 16, 0, 0);
}

// split one fp32 row-chunk of 8 into pre-swizzled [hi|lo] bf16 pair
__device__ __forceinline__ void split8_store(const float* src, unsigned short* dhi){
  float4 a = *(const float4*)src;
  float4 b = *(const float4*)(src + 4);
  float xs[8] = {a.x, a.y, a.z, a.w, b.x, b.y, b.z, b.w};
  unsigned short hi[8], lo[8];
#pragma unroll
  for (int e = 0; e < 8; ++e){
    hi[e] = f2bf_rne(xs[e]);
    lo[e] = f2bf_rne(xs[e] - bf2f(hi[e]));
  }
  uint4 ph, pl;
  ph.x = hi[0] | ((unsigned)hi[1] << 16); ph.y = hi[2] | ((unsigned)hi[3] << 16);
  ph.z = hi[4] | ((unsigned)hi[5] << 16); ph.w = hi[6] | ((unsigned)hi[7] << 16);
  pl.x = lo[0] | ((unsigned)lo[1] << 16); pl.y = lo[2] | ((unsigned)lo[3] << 16);
  pl.z = lo[4] | ((unsigned)lo[5] << 16); pl.w = lo[6] | ((unsigned)lo[7] << 16);
  *(uint4*)dhi = ph;
  *(uint4*)(dhi + 512) = pl;   // lo section lives +512 ushorts into the row
}

// ============ merged build ============
// with_xa==1: blocks [0,XB_BLOCKS) build Xa, blocks [XB_BLOCKS,+BM_BLOCKS) build Bm.
// with_xa==0: grid is BM_BLOCKS; ALL blocks build Bm only (Xa may be null) — safe fallback.
// Outputs pre-swizzled: within each 64-ushort tile, physical chunk = clog ^ (row&7), so
// gemm's linear global_load_lds + XOR'd ds_read see a consistent layout (rule #21).
__global__ void aug_build(const float* __restrict__ X,
                          const float* __restrict__ Wf, const float* __restrict__ Wi,
                          const float* __restrict__ Wh,
                          unsigned short* __restrict__ Xa, unsigned short* __restrict__ Bm,
                          int with_xa){
  int bx = blockIdx.x;
  if (with_xa && bx < XB_BLOCKS){
    int g = bx * 256 + threadIdx.x;          // [0, 32768*64)
    int row  = g >> 6;
    int tile = (g >> 3) & 7;
    int clog = g & 7;
    int cphys = clog ^ (row & 7);
    split8_store(X + (size_t)row * DIN + tile * 64 + clog * 8,
                 Xa + (size_t)row * KS + tile * 64 + cphys * 8);
  } else {
    int g = (bx - (with_xa ? XB_BLOCKS : 0)) * 256 + threadIdx.x;   // [0, 3*512*64)
    int gate = g >> 15;
    int ch   = (g >> 6) & 511;
    int tile = (g >> 3) & 7;
    int clog = g & 7;
    const float* W = (gate == 0) ? Wf : ((gate == 1) ? Wi : Wh);
    int cphys = clog ^ (ch & 7);
    split8_store(W + (size_t)ch * DIN + tile * 64 + clog * 8,
                 Bm + (size_t)(gate * 512 + ch) * KS + tile * 64 + cphys * 8);
  }
}

// ============ shared epilogue: bias + gates -> F, V ============
__device__ __forceinline__ void gate_epilogue(const f32x4 acc[4][6], int m0, int c0,
                                              int wm, int wn, int lr, int lg,
                                              const float* bfb, const float* bib, const float* bhb,
                                              float* Fw, float* Vw){
#pragma unroll
  for (int jp = 0; jp < 2; ++jp){
    int chan = c0 + wn * 16 + jp * 64 + lr;          // C/D col = lane&15  (m89/m91)
    float bfv = bfb[chan], biv = bib[chan], bhv = bhb[chan];
#pragma unroll
    for (int mi = 0; mi < 4; ++mi){
#pragma unroll
      for (int r = 0; r < 4; ++r){
        int bt = m0 + wm * 64 + mi * 16 + lg * 4 + r; // C/D row = (lane>>4)*4 + reg
        float fp = acc[mi][0 + jp][r] + bfv;
        float ip = acc[mi][2 + jp][r] + biv;
        float hp = acc[mi][4 + jp][r] + bhv;
        float zf = -fp, zi = -ip;
        float spf = fmaxf(zf, 0.f) + log1pf(expf(-fabsf(zf)));   // softplus(-f_pre)
        float spi = fmaxf(zi, 0.f) + log1pf(expf(-fabsf(zi)));   // softplus(-i_pre)
        float ef  = expf(spf - spi);                              // exp(diff)
        float fg  = 1.f / (1.f + ef);                             // forget = sigmoid(-diff)
        float g   = (hp >= 0.f) ? (hp + 0.5f) : (1.f / (1.f + expf(-hp)));  // g(h_pre)
        float v   = (1.f - fg) * g;                               // i_t * g_t
        size_t idx = (size_t)bt * DH + chan;
        Fw[idx] = fg;
        Vw[idx] = v;
      }
    }
  }
}

// ============ fast GEMM: all staging via global_load_lds(16B) ============
// 2-barrier m97-style loop; 48 MFMA per wave per K-step; LDS exactly 64 KiB.
__launch_bounds__(512, 2)
__global__ void gemm_fast(const unsigned short* __restrict__ Xa, const unsigned short* __restrict__ Bm,
                          const float* __restrict__ bfb, const float* __restrict__ bib,
                          const float* __restrict__ bhb,
                          float* __restrict__ Fw, float* __restrict__ Vw){
  __shared__ unsigned short smem[32768];   // lA [128][64] | lB [384][64]
  unsigned short* lA = smem;
  unsigned short* lB = smem + 8192;
  const int tid = threadIdx.x, wid = tid >> 6, lane = tid & 63;
  const int m0 = blockIdx.x * BM, c0 = blockIdx.y * BCH;
  const int wm = wid >> 2, wn = wid & 3, lr = lane & 15, lg = lane >> 4;

  const unsigned short* aS0 = Xa + (size_t)(m0 + (tid >> 3)) * KS + (tid & 7) * 8;
  const unsigned short* aS1 = aS0 + (size_t)64 * KS;
  const unsigned short* bS[6];
#pragma unroll
  for (int q = 0; q < 6; ++q){
    int ci = q * 512 + tid, row = ci >> 3, cp = ci & 7;
    bS[q] = Bm + (size_t)((row >> 7) * 512 + c0 + (row & 127)) * KS + cp * 8;
  }
  unsigned short* aD0 = lA + (size_t)(tid & ~63) * 8;   // wave-uniform LDS bases (m104)
  unsigned short* aD1 = aD0 + 4096;
  unsigned short* bD0 = lB + (size_t)(tid & ~63) * 8;

  f32x4 acc[4][6];
#pragma unroll
  for (int a = 0; a < 4; ++a)
#pragma unroll
    for (int b = 0; b < 6; ++b) acc[a][b] = {0.f, 0.f, 0.f, 0.f};

  for (int kt = 0; kt < NKT; ++kt){
    // section map: A = [hi, lo, hi], B = [hi, hi, lo]  (bf16x3: drop lo*lo)
    const int aoff = (kt < 16 ? kt : kt - 16) * 64;
    const int boff = (kt < 8  ? kt : kt - 8 ) * 64;
    if (kt) __syncthreads();
    gld16(aS0 + aoff, aD0);
    gld16(aS1 + aoff, aD1);
#pragma unroll
    for (int q = 0; q < 6; ++q) gld16(bS[q] + boff, bD0 + q * 4096);
    __syncthreads();   // compiler drains vmcnt(0) before s_barrier -> tiles ready
#pragma unroll
    for (int kk = 0; kk < 2; ++kk){
      bf16x8 af[4], bfr[6];
#pragma unroll
      for (int mi = 0; mi < 4; ++mi){
        int row = wm * 64 + mi * 16 + lr;
        int ch  = (kk * 4 + lg) ^ (row & 7);
        af[mi] = *(const bf16x8*)(lA + row * 64 + ch * 8);
      }
#pragma unroll
      for (int j = 0; j < 6; ++j){
        int row = wn * 16 + j * 64 + lr;    // j 0,1:f  2,3:i  4,5:h
        int ch  = (kk * 4 + lg) ^ (row & 7);
        bfr[j] = *(const bf16x8*)(lB + row * 64 + ch * 8);
      }
#pragma unroll
      for (int mi = 0; mi < 4; ++mi)
#pragma unroll
        for (int j = 0; j < 6; ++j)
          acc[mi][j] = __builtin_amdgcn_mfma_f32_16x16x32_bf16(af[mi], bfr[j], acc[mi][j], 0, 0, 0);
    }
  }
  gate_epilogue(acc, m0, c0, wm, wn, lr, lg, bfb, bib, bhb, Fw, Vw);
}

// ============ fallback GEMM (small ws): A converted in-loop, B via global_load_lds ============
__launch_bounds__(512, 2)
__global__ void gemm_slow(const float* __restrict__ X, const unsigned short* __restrict__ Bm,
                          const float* __restrict__ bfb, const float* __restrict__ bib,
                          const float* __restrict__ bhb,
                          float* __restrict__ Fw, float* __restrict__ Vw){
  __shared__ unsigned short smem[32768];
  unsigned short* lA = smem;
  unsigned short* lB = smem + 8192;
  const int tid = threadIdx.x, wid = tid >> 6, lane = tid & 63;
  const int m0 = blockIdx.x * BM, c0 = blockIdx.y * BCH;
  const int wm = wid >> 2, wn = wid & 3, lr = lane & 15, lg = lane >> 4;

  const unsigned short* bS[6];
#pragma unroll
  for (int q = 0; q < 6; ++q){
    int ci = q * 512 + tid, row = ci >> 3, cp = ci & 7;
    bS[q] = Bm + (size_t)((row >> 7) * 512 + c0 + (row & 127)) * KS + cp * 8;
  }
  unsigned short* bD0 = lB + (size_t)(tid & ~63) * 8;

  f32x4 acc[4][6];
#pragma unroll
  for (int a = 0; a < 4; ++a)
#pragma unroll
    for (int b = 0; b < 6; ++b) acc[a][b] = {0.f, 0.f, 0.f, 0.f};

  for (int kt = 0; kt < NKT; ++kt){
    const bool losec = (kt >= 8 && kt < 16);
    const int  ko    = (kt < 8 ? kt : (kt < 16 ? kt - 8 : kt - 16)) * 64;
    const int  boff  = (kt < 8 ? kt : kt - 8) * 64;
    if (kt) __syncthreads();
#pragma unroll
    for (int q = 0; q < 2; ++q){
      int ci = q * 512 + tid, row = ci >> 3, kc = ci & 7;
      const float* src = X + (size_t)(m0 + row) * DIN + ko + kc * 8;
      float4 xa = *(const float4*)src;
      float4 xb = *(const float4*)(src + 4);
      float xs[8] = {xa.x, xa.y, xa.z, xa.w, xb.x, xb.y, xb.z, xb.w};
      unsigned short hs[8];
#pragma unroll
      for (int e = 0; e < 8; ++e){
        unsigned short h = f2bf_rne(xs[e]);
        hs[e] = losec ? f2bf_rne(xs[e] - bf2f(h)) : h;
      }
      uint4 pk;
      pk.x = hs[0] | ((unsigned)hs[1] << 16); pk.y = hs[2] | ((unsigned)hs[3] << 16);
      pk.z = hs[4] | ((unsigned)hs[5] << 16); pk.w = hs[6] | ((unsigned)hs[7] << 16);
      *(uint4*)(lA + row * 64 + ((kc ^ (row & 7)) * 8)) = pk;
    }
#pragma unroll
    for (int q = 0; q < 6; ++q) gld16(bS[q] + boff, bD0 + q * 4096);
    __syncthreads();
#pragma unroll
    for (int kk = 0; kk < 2; ++kk){
      bf16x8 af[4], bfr[6];
#pragma unroll
      for (int mi = 0; mi < 4; ++mi){
        int row = wm * 64 + mi * 16 + lr;
        int ch  = (kk * 4 + lg) ^ (row & 7);
        af[mi] = *(const bf16x8*)(lA + row * 64 + ch * 8);
      }
#pragma unroll
      for (int j = 0; j < 6; ++j){
        int row = wn * 16 + j * 64 + lr;
        int ch  = (kk * 4 + lg) ^ (row & 7);
        bfr[j] = *(const bf16x8*)(lB + row * 64 + ch * 8);
      }
#pragma unroll
      for (int mi = 0; mi < 4; ++mi)
#pragma unroll
        for (int j = 0; j < 6; ++j)
          acc[mi][j] = __builtin_amdgcn_mfma_f32_16x16x32_bf16(af[mi], bfr[j], acc[mi][j], 0, 0, 0);
    }
  }
  gate_epilogue(acc, m0, c0, wm, wn, lr, lg, bfb, bib, bhb, Fw, Vw);
}

// ============ scan phase A: per-chunk composition, float4 over 4 channels/thread ============
// grid: 256 blocks (chunk*4 + b), 128 threads; thread handles channels tid*4..+3
__global__ void scan_chunks(const float* __restrict__ Fw, const float* __restrict__ Vw,
                            float2* __restrict__ S){
  int bx = blockIdx.x;
  int chunk = bx >> 2, b = bx & 3;
  int ch4 = threadIdx.x * 4;
  size_t base = ((size_t)(b * T_SEQ + chunk * CHUNK_L)) * DH + ch4;
  float4 Fc = make_float4(1.f, 1.f, 1.f, 1.f);
  float4 Vc = make_float4(0.f, 0.f, 0.f, 0.f);
#pragma unroll 8
  for (int t = 0; t < CHUNK_L; ++t){
    float4 f = *(const float4*)(Fw + base + (size_t)t * DH);
    float4 v = *(const float4*)(Vw + base + (size_t)t * DH);
    Fc.x *= f.x; Fc.y *= f.y; Fc.z *= f.z; Fc.w *= f.w;
    Vc.x = fmaf(f.x, Vc.x, v.x); Vc.y = fmaf(f.y, Vc.y, v.y);
    Vc.z = fmaf(f.z, Vc.z, v.z); Vc.w = fmaf(f.w, Vc.w, v.w);
  }
  float2* s = S + (size_t)chunk * NCH_TOT + b * DH + ch4;
  s[0] = make_float2(Fc.x, Vc.x);
  s[1] = make_float2(Fc.y, Vc.y);
  s[2] = make_float2(Fc.z, Vc.z);
  s[3] = make_float2(Fc.w, Vc.w);
}

// ============ scan phase B: carry across chunks; seed = g(h0) ============
__global__ void scan_carry(const float2* __restrict__ S, const float* __restrict__ h0,
                           float* __restrict__ Hs){
  int cg = blockIdx.x * 256 + threadIdx.x;   // b*DH + chan
  float hv = h0[cg];
  float h = (hv >= 0.f) ? (hv + 0.5f) : (1.f / (1.f + expf(-hv)));  // g(h0) — the scan seed!
  float2 s = S[cg];
#pragma unroll 16
  for (int k = 0; k < NCHUNK; ++k){
    float2 snext = (k + 1 < NCHUNK) ? S[(k + 1) * NCH_TOT + cg] : make_float2(0.f, 0.f);
    Hs[k * NCH_TOT + cg] = h;
    h = fmaf(s.x, h, s.y);
    s = snext;
  }
}

// ============ scan phase C: replay + write output, float4 over 4 channels/thread ============
// grid: 256 blocks (chunk*4 + b), 128 threads; V lives in d_out, overwritten in place
__global__ void scan_apply(const float* __restrict__ Fw, const float* Vw,
                           const float* __restrict__ Hs, float* out){
  int bx = blockIdx.x;
  int chunk = bx >> 2, b = bx & 3;
  int ch4 = threadIdx.x * 4;
  float4 h = *(const float4*)(Hs + (size_t)chunk * NCH_TOT + b * DH + ch4);
  size_t base = ((size_t)(b * T_SEQ + chunk * CHUNK_L)) * DH + ch4;
#pragma unroll 8
  for (int t = 0; t < CHUNK_L; ++t){
    size_t idx = base + (size_t)t * DH;
    float4 f = *(const float4*)(Fw + idx);
    float4 v = *(const float4*)(Vw + idx);     // read-before-overwrite, same thread
    h.x = fmaf(f.x, h.x, v.x); h.y = fmaf(f.y, h.y, v.y);
    h.z = fmaf(f.z, h.z, v.z); h.w = fmaf(f.w, h.w, v.w);
    *(float4*)(out + idx) = h;
  }
}

extern "C" void kernel_launch(void* const* d_in, const int* in_sizes, int n_in,
                              void* d_out, int out_size, void* d_ws, size_t ws_size,
                              hipStream_t stream){
  (void)in_sizes; (void)n_in; (void)out_size;
  const float* X  = (const float*)d_in[0];
  const float* h0 = (const float*)d_in[1];
  const float* Wf = (const float*)d_in[2];
  const float* bf = (const float*)d_in[3];
  const float* Wi = (const float*)d_in[4];
  const float* bi = (const float*)d_in[5];
  const float* Wh = (const float*)d_in[6];
  const float* bh = (const float*)d_in[7];

  constexpr size_t XA_B = (size_t)M_TOT * KS * 2;        // 64 MiB
  constexpr size_t F_B  = (size_t)M_TOT * DH * 4;        // 64 MiB
  constexpr size_t S_B  = (size_t)NCHUNK * NCH_TOT * 8;  // 1 MiB
  constexpr size_t H_B  = (size_t)NCHUNK * NCH_TOT * 4;  // 0.5 MiB
  constexpr size_t BMB  = (size_t)3 * 512 * KS * 2;      // 3 MiB
  const bool fast = ws_size >= XA_B + F_B + S_B + H_B + BMB;

  char* ws = (char*)d_ws;
  float* Vw  = (float*)d_out;     // V shares d_out; scan_apply overwrites in place
  float* out = (float*)d_out;

  if (fast){
    unsigned short* Xa  = (unsigned short*)ws;
    float*          Fw  = (float*)(ws + XA_B);
    float2*         S   = (float2*)(ws + XA_B + F_B);
    float*          Hs  = (float*)(ws + XA_B + F_B + S_B);
    unsigned short* Bmw = (unsigned short*)(ws + XA_B + F_B + S_B + H_B);
    aug_build <<<XB_BLOCKS + BM_BLOCKS, 256, 0, stream>>>(X, Wf, Wi, Wh, Xa, Bmw, 1);
    gemm_fast <<<dim3(M_TOT / BM, DH / BCH), 512, 0, stream>>>(Xa, Bmw, bf, bi, bh, Fw, Vw);
    scan_chunks<<<256, 128, 0, stream>>>(Fw, Vw, S);
    scan_carry <<<8, 256, 0, stream>>>(S, h0, Hs);
    scan_apply <<<256, 128, 0, stream>>>(Fw, Vw, Hs, out);
  } else {
    float*          Fw  = (float*)ws;
    float2*         S   = (float2*)(ws + F_B);
    float*          Hs  = (float*)(ws + F_B + S_B);
    unsigned short* Bmw = (unsigned short*)(ws + F_B + S_B + H_B);
    aug_build <<<BM_BLOCKS, 256, 0, stream>>>(X, Wf, Wi, Wh, nullptr, Bmw, 0);
    gemm_slow <<<dim3(M_TOT / BM, DH / BCH), 512, 0, stream>>>(X, Bmw, bf, bi, bh, Fw, Vw);
    scan_chunks<<<256, 128, 0, stream>>>(Fw, Vw, S);
    scan_carry <<<8, 256, 0, stream>>>(S, h0, Hs);
    scan_apply <<<256, 128, 0, stream>>>(Fw, Vw, Hs, out);
  }
}

// Round 7
// 451.010 us; speedup vs baseline: 1.1074x; 1.1074x over previous
//
#include <hip/hip_runtime.h>
#include <hip/hip_bf16.h>
#include <stdint.h>

#define T_SEQ 8192
#define BB    4
#define DH    512
#define DIN   512
#define M_TOT (BB*T_SEQ)          // 32768
#define BM    128
#define BCH   128                 // channels per block -> 3*BCH = 384 N-rows in LDS
#define BK    64
#define NKT   24                  // K_aug = 1536 = 24 * 64 (A=[hi,lo,hi] x B=[hi,hi,lo])
#define KS    1024                // stored ushorts per row: [hi(512) | lo(512)]
#define CHUNK_L 128
#define NCHUNK  64
#define NCH_TOT (BB*DH)           // 2048
#define GRID_WG 1024              // (M_TOT/BM) * (DH/BCH)

#define XB_BLOCKS 8192            // xaug part of merged build kernel
#define BM_BLOCKS 384             // bmat part

typedef __attribute__((ext_vector_type(4))) float f32x4;
typedef __attribute__((ext_vector_type(8))) short bf16x8;

__device__ __forceinline__ unsigned short f2bf_rne(float x){
  unsigned u = __float_as_uint(x);
  return (unsigned short)((u + 0x7FFFu + ((u >> 16) & 1u)) >> 16);
}
__device__ __forceinline__ float bf2f(unsigned short h){
  return __uint_as_float(((unsigned)h) << 16);
}
__device__ __forceinline__ void gld16(const void* g, void* l){
  __builtin_amdgcn_global_load_lds((const __attribute__((address_space(1))) unsigned*)g,
                                   (__attribute__((address_space(3))) unsigned*)l, 16, 0, 0);
}

// split one fp32 row-chunk of 8 into pre-swizzled [hi|lo] bf16 pair
__device__ __forceinline__ void split8_store(const float* src, unsigned short* dhi){
  float4 a = *(const float4*)src;
  float4 b = *(const float4*)(src + 4);
  float xs[8] = {a.x, a.y, a.z, a.w, b.x, b.y, b.z, b.w};
  unsigned short hi[8], lo[8];
#pragma unroll
  for (int e = 0; e < 8; ++e){
    hi[e] = f2bf_rne(xs[e]);
    lo[e] = f2bf_rne(xs[e] - bf2f(hi[e]));
  }
  uint4 ph, pl;
  ph.x = hi[0] | ((unsigned)hi[1] << 16); ph.y = hi[2] | ((unsigned)hi[3] << 16);
  ph.z = hi[4] | ((unsigned)hi[5] << 16); ph.w = hi[6] | ((unsigned)hi[7] << 16);
  pl.x = lo[0] | ((unsigned)lo[1] << 16); pl.y = lo[2] | ((unsigned)lo[3] << 16);
  pl.z = lo[4] | ((unsigned)lo[5] << 16); pl.w = lo[6] | ((unsigned)lo[7] << 16);
  *(uint4*)dhi = ph;
  *(uint4*)(dhi + 512) = pl;   // lo section lives +512 ushorts into the row
}

// ============ merged build ============
__global__ void aug_build(const float* __restrict__ X,
                          const float* __restrict__ Wf, const float* __restrict__ Wi,
                          const float* __restrict__ Wh,
                          unsigned short* __restrict__ Xa, unsigned short* __restrict__ Bm,
                          int with_xa){
  int bx = blockIdx.x;
  if (with_xa && bx < XB_BLOCKS){
    int g = bx * 256 + threadIdx.x;          // [0, 32768*64)
    int row  = g >> 6;
    int tile = (g >> 3) & 7;
    int clog = g & 7;
    int cphys = clog ^ (row & 7);
    split8_store(X + (size_t)row * DIN + tile * 64 + clog * 8,
                 Xa + (size_t)row * KS + tile * 64 + cphys * 8);
  } else {
    int g = (bx - (with_xa ? XB_BLOCKS : 0)) * 256 + threadIdx.x;   // [0, 3*512*64)
    int gate = g >> 15;
    int ch   = (g >> 6) & 511;
    int tile = (g >> 3) & 7;
    int clog = g & 7;
    const float* W = (gate == 0) ? Wf : ((gate == 1) ? Wi : Wh);
    int cphys = clog ^ (ch & 7);
    split8_store(W + (size_t)ch * DIN + tile * 64 + clog * 8,
                 Bm + (size_t)(gate * 512 + ch) * KS + tile * 64 + cphys * 8);
  }
}

// ============ shared epilogue: bias + gates -> F, V ============
__device__ __forceinline__ void gate_epilogue(const f32x4 acc[4][6], int m0, int c0,
                                              int wm, int wn, int lr, int lg,
                                              const float* bfb, const float* bib, const float* bhb,
                                              float* Fw, float* Vw){
#pragma unroll
  for (int jp = 0; jp < 2; ++jp){
    int chan = c0 + wn * 16 + jp * 64 + lr;          // C/D col = lane&15  (m89/m91)
    float bfv = bfb[chan], biv = bib[chan], bhv = bhb[chan];
#pragma unroll
    for (int mi = 0; mi < 4; ++mi){
#pragma unroll
      for (int r = 0; r < 4; ++r){
        int bt = m0 + wm * 64 + mi * 16 + lg * 4 + r; // C/D row = (lane>>4)*4 + reg
        float fp = acc[mi][0 + jp][r] + bfv;
        float ip = acc[mi][2 + jp][r] + biv;
        float hp = acc[mi][4 + jp][r] + bhv;
        float zf = -fp, zi = -ip;
        float spf = fmaxf(zf, 0.f) + log1pf(expf(-fabsf(zf)));   // softplus(-f_pre)
        float spi = fmaxf(zi, 0.f) + log1pf(expf(-fabsf(zi)));   // softplus(-i_pre)
        float ef  = expf(spf - spi);                              // exp(diff)
        float fg  = 1.f / (1.f + ef);                             // forget = sigmoid(-diff)
        float g   = (hp >= 0.f) ? (hp + 0.5f) : (1.f / (1.f + expf(-hp)));  // g(h_pre)
        float v   = (1.f - fg) * g;                               // i_t * g_t
        size_t idx = (size_t)bt * DH + chan;
        Fw[idx] = fg;
        Vw[idx] = v;
      }
    }
  }
}

// ============ fast GEMM: 2-phase double-buffered global_load_lds staging ============
// Per K-step: issue next tile's 8 gld16 into buf^1, compute on buf, ONE trailing
// barrier (its vmcnt(0) drain lands after compute has hidden the load latency).
// 128 KiB LDS (1 block/CU — regs cap at 2 waves/SIMD anyway). XCD-chunked swizzle.
__launch_bounds__(512, 2)
__global__ void gemm_fast(const unsigned short* __restrict__ Xa, const unsigned short* __restrict__ Bm,
                          const float* __restrict__ bfb, const float* __restrict__ bib,
                          const float* __restrict__ bhb,
                          float* __restrict__ Fw, float* __restrict__ Vw){
  __shared__ unsigned short smem[65536];   // 128 KiB: 2 x {lA [128][64] | lB [384][64]}
  const int tid = threadIdx.x, wid = tid >> 6, lane = tid & 63;
  // bijective chunked XCD swizzle (GRID_WG % 8 == 0): neighbors (same A-panel) share an XCD L2
  const int wg = (blockIdx.x & 7) * (GRID_WG / 8) + (blockIdx.x >> 3);
  const int m0 = (wg >> 2) * BM, c0 = (wg & 3) * BCH;
  const int wm = wid >> 2, wn = wid & 3, lr = lane & 15, lg = lane >> 4;

  const unsigned short* aS0 = Xa + (size_t)(m0 + (tid >> 3)) * KS + (tid & 7) * 8;
  const unsigned short* aS1 = aS0 + (size_t)64 * KS;
  const unsigned short* bS[6];
#pragma unroll
  for (int q = 0; q < 6; ++q){
    int ci = q * 512 + tid, row = ci >> 3, cp = ci & 7;
    bS[q] = Bm + (size_t)((row >> 7) * 512 + c0 + (row & 127)) * KS + cp * 8;
  }
  const int ldst = (tid & ~63) * 8;        // wave-uniform LDS element base (m104)

  f32x4 acc[4][6];
#pragma unroll
  for (int a = 0; a < 4; ++a)
#pragma unroll
    for (int b = 0; b < 6; ++b) acc[a][b] = {0.f, 0.f, 0.f, 0.f};

  // stage tile kt into buffer buf (A = [hi, lo, hi], B = [hi, hi, lo])
  auto stage = [&](int kt, unsigned short* buf){
    const int aoff = (kt < 16 ? kt : kt - 16) * 64;
    const int boff = (kt < 8  ? kt : kt - 8 ) * 64;
    unsigned short* aD = buf + ldst;
    gld16(aS0 + aoff, aD);
    gld16(aS1 + aoff, aD + 4096);
    unsigned short* bD = buf + 8192 + ldst;
#pragma unroll
    for (int q = 0; q < 6; ++q) gld16(bS[q] + boff, bD + q * 4096);
  };

  stage(0, smem);
  __syncthreads();                          // drain prologue stage
  int cur = 0;
  for (int kt = 0; kt < NKT; ++kt){
    if (kt + 1 < NKT) stage(kt + 1, smem + (cur ^ 1) * 32768);   // issue, don't wait
    unsigned short* lA = smem + cur * 32768;
    unsigned short* lB = lA + 8192;
#pragma unroll
    for (int kk = 0; kk < 2; ++kk){
      bf16x8 af[4], bfr[6];
#pragma unroll
      for (int mi = 0; mi < 4; ++mi){
        int row = wm * 64 + mi * 16 + lr;
        int ch  = (kk * 4 + lg) ^ (row & 7);
        af[mi] = *(const bf16x8*)(lA + row * 64 + ch * 8);
      }
#pragma unroll
      for (int j = 0; j < 6; ++j){
        int row = wn * 16 + j * 64 + lr;    // j 0,1:f  2,3:i  4,5:h
        int ch  = (kk * 4 + lg) ^ (row & 7);
        bfr[j] = *(const bf16x8*)(lB + row * 64 + ch * 8);
      }
#pragma unroll
      for (int mi = 0; mi < 4; ++mi)
#pragma unroll
        for (int j = 0; j < 6; ++j)
          acc[mi][j] = __builtin_amdgcn_mfma_f32_16x16x32_bf16(af[mi], bfr[j], acc[mi][j], 0, 0, 0);
    }
    __syncthreads();   // drains vmcnt(0): next tile ready; orders reads before overwrite
    cur ^= 1;
  }
  gate_epilogue(acc, m0, c0, wm, wn, lr, lg, bfb, bib, bhb, Fw, Vw);
}

// ============ fallback GEMM (small ws): single-buffered, A converted in-loop ============
__launch_bounds__(512, 2)
__global__ void gemm_slow(const float* __restrict__ X, const unsigned short* __restrict__ Bm,
                          const float* __restrict__ bfb, const float* __restrict__ bib,
                          const float* __restrict__ bhb,
                          float* __restrict__ Fw, float* __restrict__ Vw){
  __shared__ unsigned short smem[32768];
  unsigned short* lA = smem;
  unsigned short* lB = smem + 8192;
  const int tid = threadIdx.x, wid = tid >> 6, lane = tid & 63;
  const int m0 = blockIdx.x * BM, c0 = blockIdx.y * BCH;
  const int wm = wid >> 2, wn = wid & 3, lr = lane & 15, lg = lane >> 4;

  const unsigned short* bS[6];
#pragma unroll
  for (int q = 0; q < 6; ++q){
    int ci = q * 512 + tid, row = ci >> 3, cp = ci & 7;
    bS[q] = Bm + (size_t)((row >> 7) * 512 + c0 + (row & 127)) * KS + cp * 8;
  }
  unsigned short* bD0 = lB + (size_t)(tid & ~63) * 8;

  f32x4 acc[4][6];
#pragma unroll
  for (int a = 0; a < 4; ++a)
#pragma unroll
    for (int b = 0; b < 6; ++b) acc[a][b] = {0.f, 0.f, 0.f, 0.f};

  for (int kt = 0; kt < NKT; ++kt){
    const bool losec = (kt >= 8 && kt < 16);
    const int  ko    = (kt < 8 ? kt : (kt < 16 ? kt - 8 : kt - 16)) * 64;
    const int  boff  = (kt < 8 ? kt : kt - 8) * 64;
    if (kt) __syncthreads();
#pragma unroll
    for (int q = 0; q < 2; ++q){
      int ci = q * 512 + tid, row = ci >> 3, kc = ci & 7;
      const float* src = X + (size_t)(m0 + row) * DIN + ko + kc * 8;
      float4 xa = *(const float4*)src;
      float4 xb = *(const float4*)(src + 4);
      float xs[8] = {xa.x, xa.y, xa.z, xa.w, xb.x, xb.y, xb.z, xb.w};
      unsigned short hs[8];
#pragma unroll
      for (int e = 0; e < 8; ++e){
        unsigned short h = f2bf_rne(xs[e]);
        hs[e] = losec ? f2bf_rne(xs[e] - bf2f(h)) : h;
      }
      uint4 pk;
      pk.x = hs[0] | ((unsigned)hs[1] << 16); pk.y = hs[2] | ((unsigned)hs[3] << 16);
      pk.z = hs[4] | ((unsigned)hs[5] << 16); pk.w = hs[6] | ((unsigned)hs[7] << 16);
      *(uint4*)(lA + row * 64 + ((kc ^ (row & 7)) * 8)) = pk;
    }
#pragma unroll
    for (int q = 0; q < 6; ++q) gld16(bS[q] + boff, bD0 + q * 4096);
    __syncthreads();
#pragma unroll
    for (int kk = 0; kk < 2; ++kk){
      bf16x8 af[4], bfr[6];
#pragma unroll
      for (int mi = 0; mi < 4; ++mi){
        int row = wm * 64 + mi * 16 + lr;
        int ch  = (kk * 4 + lg) ^ (row & 7);
        af[mi] = *(const bf16x8*)(lA + row * 64 + ch * 8);
      }
#pragma unroll
      for (int j = 0; j < 6; ++j){
        int row = wn * 16 + j * 64 + lr;
        int ch  = (kk * 4 + lg) ^ (row & 7);
        bfr[j] = *(const bf16x8*)(lB + row * 64 + ch * 8);
      }
#pragma unroll
      for (int mi = 0; mi < 4; ++mi)
#pragma unroll
        for (int j = 0; j < 6; ++j)
          acc[mi][j] = __builtin_amdgcn_mfma_f32_16x16x32_bf16(af[mi], bfr[j], acc[mi][j], 0, 0, 0);
    }
  }
  gate_epilogue(acc, m0, c0, wm, wn, lr, lg, bfb, bib, bhb, Fw, Vw);
}

// ============ scan phase A: per-chunk composition, float4 over 4 channels/thread ============
__global__ void scan_chunks(const float* __restrict__ Fw, const float* __restrict__ Vw,
                            float2* __restrict__ S){
  int bx = blockIdx.x;
  int chunk = bx >> 2, b = bx & 3;
  int ch4 = threadIdx.x * 4;
  size_t base = ((size_t)(b * T_SEQ + chunk * CHUNK_L)) * DH + ch4;
  float4 Fc = make_float4(1.f, 1.f, 1.f, 1.f);
  float4 Vc = make_float4(0.f, 0.f, 0.f, 0.f);
#pragma unroll 8
  for (int t = 0; t < CHUNK_L; ++t){
    float4 f = *(const float4*)(Fw + base + (size_t)t * DH);
    float4 v = *(const float4*)(Vw + base + (size_t)t * DH);
    Fc.x *= f.x; Fc.y *= f.y; Fc.z *= f.z; Fc.w *= f.w;
    Vc.x = fmaf(f.x, Vc.x, v.x); Vc.y = fmaf(f.y, Vc.y, v.y);
    Vc.z = fmaf(f.z, Vc.z, v.z); Vc.w = fmaf(f.w, Vc.w, v.w);
  }
  float2* s = S + (size_t)chunk * NCH_TOT + b * DH + ch4;
  s[0] = make_float2(Fc.x, Vc.x);
  s[1] = make_float2(Fc.y, Vc.y);
  s[2] = make_float2(Fc.z, Vc.z);
  s[3] = make_float2(Fc.w, Vc.w);
}

// ============ scan phase B: carry across chunks; seed = g(h0) ============
__global__ void scan_carry(const float2* __restrict__ S, const float* __restrict__ h0,
                           float* __restrict__ Hs){
  int cg = blockIdx.x * 256 + threadIdx.x;   // b*DH + chan
  float hv = h0[cg];
  float h = (hv >= 0.f) ? (hv + 0.5f) : (1.f / (1.f + expf(-hv)));  // g(h0) — the scan seed!
  float2 s = S[cg];
#pragma unroll 16
  for (int k = 0; k < NCHUNK; ++k){
    float2 snext = (k + 1 < NCHUNK) ? S[(k + 1) * NCH_TOT + cg] : make_float2(0.f, 0.f);
    Hs[k * NCH_TOT + cg] = h;
    h = fmaf(s.x, h, s.y);
    s = snext;
  }
}

// ============ scan phase C: replay + write output, float4 over 4 channels/thread ============
__global__ void scan_apply(const float* __restrict__ Fw, const float* Vw,
                           const float* __restrict__ Hs, float* out){
  int bx = blockIdx.x;
  int chunk = bx >> 2, b = bx & 3;
  int ch4 = threadIdx.x * 4;
  float4 h = *(const float4*)(Hs + (size_t)chunk * NCH_TOT + b * DH + ch4);
  size_t base = ((size_t)(b * T_SEQ + chunk * CHUNK_L)) * DH + ch4;
#pragma unroll 8
  for (int t = 0; t < CHUNK_L; ++t){
    size_t idx = base + (size_t)t * DH;
    float4 f = *(const float4*)(Fw + idx);
    float4 v = *(const float4*)(Vw + idx);     // read-before-overwrite, same thread
    h.x = fmaf(f.x, h.x, v.x); h.y = fmaf(f.y, h.y, v.y);
    h.z = fmaf(f.z, h.z, v.z); h.w = fmaf(f.w, h.w, v.w);
    *(float4*)(out + idx) = h;
  }
}

extern "C" void kernel_launch(void* const* d_in, const int* in_sizes, int n_in,
                              void* d_out, int out_size, void* d_ws, size_t ws_size,
                              hipStream_t stream){
  (void)in_sizes; (void)n_in; (void)out_size;
  const float* X  = (const float*)d_in[0];
  const float* h0 = (const float*)d_in[1];
  const float* Wf = (const float*)d_in[2];
  const float* bf = (const float*)d_in[3];
  const float* Wi = (const float*)d_in[4];
  const float* bi = (const float*)d_in[5];
  const float* Wh = (const float*)d_in[6];
  const float* bh = (const float*)d_in[7];

  constexpr size_t XA_B = (size_t)M_TOT * KS * 2;        // 64 MiB
  constexpr size_t F_B  = (size_t)M_TOT * DH * 4;        // 64 MiB
  constexpr size_t S_B  = (size_t)NCHUNK * NCH_TOT * 8;  // 1 MiB
  constexpr size_t H_B  = (size_t)NCHUNK * NCH_TOT * 4;  // 0.5 MiB
  constexpr size_t BMB  = (size_t)3 * 512 * KS * 2;      // 3 MiB
  const bool fast = ws_size >= XA_B + F_B + S_B + H_B + BMB;

  char* ws = (char*)d_ws;
  float* Vw  = (float*)d_out;     // V shares d_out; scan_apply overwrites in place
  float* out = (float*)d_out;

  if (fast){
    unsigned short* Xa  = (unsigned short*)ws;
    float*          Fw  = (float*)(ws + XA_B);
    float2*         S   = (float2*)(ws + XA_B + F_B);
    float*          Hs  = (float*)(ws + XA_B + F_B + S_B);
    unsigned short* Bmw = (unsigned short*)(ws + XA_B + F_B + S_B + H_B);
    aug_build <<<XB_BLOCKS + BM_BLOCKS, 256, 0, stream>>>(X, Wf, Wi, Wh, Xa, Bmw, 1);
    gemm_fast <<<GRID_WG, 512, 0, stream>>>(Xa, Bmw, bf, bi, bh, Fw, Vw);
    scan_chunks<<<256, 128, 0, stream>>>(Fw, Vw, S);
    scan_carry <<<8, 256, 0, stream>>>(S, h0, Hs);
    scan_apply <<<256, 128, 0, stream>>>(Fw, Vw, Hs, out);
  } else {
    float*          Fw  = (float*)ws;
    float2*         S   = (float2*)(ws + F_B);
    float*          Hs  = (float*)(ws + F_B + S_B);
    unsigned short* Bmw = (unsigned short*)(ws + F_B + S_B + H_B);
    aug_build <<<BM_BLOCKS, 256, 0, stream>>>(X, Wf, Wi, Wh, nullptr, Bmw, 0);
    gemm_slow <<<dim3(M_TOT / BM, DH / BCH), 512, 0, stream>>>(X, Bmw, bf, bi, bh, Fw, Vw);
    scan_chunks<<<256, 128, 0, stream>>>(Fw, Vw, S);
    scan_carry <<<8, 256, 0, stream>>>(S, h0, Hs);
    scan_apply <<<256, 128, 0, stream>>>(Fw, Vw, Hs, out);
  }
}

// Round 9
// 449.491 us; speedup vs baseline: 1.1111x; 1.0034x over previous
//
#include <hip/hip_runtime.h>
#include <hip/hip_bf16.h>
#include <stdint.h>

#define T_SEQ 8192
#define BB    4
#define DH    512
#define DIN   512
#define M_TOT (BB*T_SEQ)          // 32768
#define BM    128
#define BCH   64                  // channels per block -> 3*BCH = 192 B-rows in LDS
#define BK    64
#define NKT   24                  // K_aug = 1536 (A=[hi,lo,hi] x B=[hi,hi,lo])
#define KS    1024                // stored ushorts per row: [hi(512) | lo(512)]
#define CHUNK_L 128
#define NCHUNK  64
#define NCH_TOT (BB*DH)           // 2048
#define GRID_WG 2048              // (M_TOT/BM) * (DH/BCH)
#define LDS_HALF 20480            // ushorts per buffer: A 8192 + B 12288 (40 KiB)

#define XB_BLOCKS 8192
#define BM_BLOCKS 384

typedef __attribute__((ext_vector_type(4))) float f32x4;
typedef __attribute__((ext_vector_type(8))) short bf16x8;

__device__ __forceinline__ unsigned short f2bf_rne(float x){
  unsigned u = __float_as_uint(x);
  return (unsigned short)((u + 0x7FFFu + ((u >> 16) & 1u)) >> 16);
}
__device__ __forceinline__ float bf2f(unsigned short h){
  return __uint_as_float(((unsigned)h) << 16);
}
__device__ __forceinline__ void gld16(const void* g, void* l){
  __builtin_amdgcn_global_load_lds((const __attribute__((address_space(1))) unsigned*)g,
                                   (__attribute__((address_space(3))) unsigned*)l, 16, 0, 0);
}

__device__ __forceinline__ void split8_store(const float* src, unsigned short* dhi){
  float4 a = *(const float4*)src;
  float4 b = *(const float4*)(src + 4);
  float xs[8] = {a.x, a.y, a.z, a.w, b.x, b.y, b.z, b.w};
  unsigned short hi[8], lo[8];
#pragma unroll
  for (int e = 0; e < 8; ++e){
    hi[e] = f2bf_rne(xs[e]);
    lo[e] = f2bf_rne(xs[e] - bf2f(hi[e]));
  }
  uint4 ph, pl;
  ph.x = hi[0] | ((unsigned)hi[1] << 16); ph.y = hi[2] | ((unsigned)hi[3] << 16);
  ph.z = hi[4] | ((unsigned)hi[5] << 16); ph.w = hi[6] | ((unsigned)hi[7] << 16);
  pl.x = lo[0] | ((unsigned)lo[1] << 16); pl.y = lo[2] | ((unsigned)lo[3] << 16);
  pl.z = lo[4] | ((unsigned)lo[5] << 16); pl.w = lo[6] | ((unsigned)lo[7] << 16);
  *(uint4*)dhi = ph;
  *(uint4*)(dhi + 512) = pl;
}

// ============ merged build (pre-swizzled: phys chunk = clog ^ (row&7)) ============
__global__ void aug_build(const float* __restrict__ X,
                          const float* __restrict__ Wf, const float* __restrict__ Wi,
                          const float* __restrict__ Wh,
                          unsigned short* __restrict__ Xa, unsigned short* __restrict__ Bm,
                          int with_xa){
  int bx = blockIdx.x;
  if (with_xa && bx < XB_BLOCKS){
    int g = bx * 256 + threadIdx.x;
    int row  = g >> 6;
    int tile = (g >> 3) & 7;
    int clog = g & 7;
    int cphys = clog ^ (row & 7);
    split8_store(X + (size_t)row * DIN + tile * 64 + clog * 8,
                 Xa + (size_t)row * KS + tile * 64 + cphys * 8);
  } else {
    int g = (bx - (with_xa ? XB_BLOCKS : 0)) * 256 + threadIdx.x;
    int gate = g >> 15;
    int ch   = (g >> 6) & 511;
    int tile = (g >> 3) & 7;
    int clog = g & 7;
    const float* W = (gate == 0) ? Wf : ((gate == 1) ? Wi : Wh);
    int cphys = clog ^ (ch & 7);
    split8_store(W + (size_t)ch * DIN + tile * 64 + clog * 8,
                 Bm + (size_t)(gate * 512 + ch) * KS + tile * 64 + cphys * 8);
  }
}

// ============ epilogue: bias + gates -> F, V (acc[mi][gate]) ============
__device__ __forceinline__ void gate_epilogue3(const f32x4 acc[4][3], int m0, int c0,
                                               int wm, int wn, int lr, int lg,
                                               const float* bfb, const float* bib, const float* bhb,
                                               float* Fw, float* Vw){
  int chan = c0 + wn * 16 + lr;                      // C/D col = lane&15 (m89/m91)
  float bfv = bfb[chan], biv = bib[chan], bhv = bhb[chan];
#pragma unroll
  for (int mi = 0; mi < 4; ++mi){
#pragma unroll
    for (int r = 0; r < 4; ++r){
      int bt = m0 + wm * 64 + mi * 16 + lg * 4 + r;  // C/D row = (lane>>4)*4 + reg
      float fp = acc[mi][0][r] + bfv;
      float ip = acc[mi][1][r] + biv;
      float hp = acc[mi][2][r] + bhv;
      float zf = -fp, zi = -ip;
      float spf = fmaxf(zf, 0.f) + log1pf(expf(-fabsf(zf)));   // softplus(-f_pre)
      float spi = fmaxf(zi, 0.f) + log1pf(expf(-fabsf(zi)));   // softplus(-i_pre)
      float ef  = expf(spf - spi);                              // exp(diff)
      float fg  = 1.f / (1.f + ef);                             // forget = sigmoid(-diff)
      float g   = (hp >= 0.f) ? (hp + 0.5f) : (1.f / (1.f + expf(-hp)));
      float v   = (1.f - fg) * g;                               // i_t * g_t
      size_t idx = (size_t)bt * DH + chan;
      Fw[idx] = fg;
      Vw[idx] = v;
    }
  }
}

// ============ fast GEMM: 2-phase dbuf, BCH=64 -> acc[4][3]=48 AGPR, 2 blocks/CU ============
// LDS 80 KiB (2 x 40 KiB) -> two resident blocks per CU (160 KiB pool) at 4 waves/SIMD,
// restoring the cross-block wave overlap (m114) that hides staging + barrier drain.
__launch_bounds__(512, 4)
__global__ void gemm_fast(const unsigned short* __restrict__ Xa, const unsigned short* __restrict__ Bm,
                          const float* __restrict__ bfb, const float* __restrict__ bib,
                          const float* __restrict__ bhb,
                          float* __restrict__ Fw, float* __restrict__ Vw){
  __shared__ unsigned short smem[2 * LDS_HALF];      // 80 KiB
  const int tid = threadIdx.x, wid = tid >> 6, lane = tid & 63;
  // bijective chunked XCD swizzle (GRID_WG % 8 == 0): XCD k owns 32 contiguous m-panels x 8 c
  const int wg = (blockIdx.x & 7) * (GRID_WG / 8) + (blockIdx.x >> 3);
  const int m0 = (wg >> 3) * BM, c0 = (wg & 7) * BCH;
  const int wm = wid >> 2, wn = wid & 3, lr = lane & 15, lg = lane >> 4;

  const unsigned short* aS0 = Xa + (size_t)(m0 + (tid >> 3)) * KS + (tid & 7) * 8;
  const unsigned short* aS1 = aS0 + (size_t)64 * KS;
  const unsigned short* bS[3];
#pragma unroll
  for (int q = 0; q < 3; ++q){
    int ci = q * 512 + tid, row = ci >> 3, cp = ci & 7;   // row in [0,192)
    bS[q] = Bm + (size_t)((row >> 6) * 512 + c0 + (row & 63)) * KS + cp * 8;
  }
  const int ldst = (tid & ~63) * 8;                  // wave-uniform LDS base (m104)

  f32x4 acc[4][3];
#pragma unroll
  for (int a = 0; a < 4; ++a)
#pragma unroll
    for (int b = 0; b < 3; ++b) acc[a][b] = {0.f, 0.f, 0.f, 0.f};

  auto stage = [&](int kt, unsigned short* buf){     // A=[hi,lo,hi], B=[hi,hi,lo]
    const int aoff = (kt < 16 ? kt : kt - 16) * 64;
    const int boff = (kt < 8  ? kt : kt - 8 ) * 64;
    unsigned short* aD = buf + ldst;
    gld16(aS0 + aoff, aD);
    gld16(aS1 + aoff, aD + 4096);
    unsigned short* bD = buf + 8192 + ldst;
#pragma unroll
    for (int q = 0; q < 3; ++q) gld16(bS[q] + boff, bD + q * 4096);
  };

  stage(0, smem);
  __syncthreads();
  int cur = 0;
  for (int kt = 0; kt < NKT; ++kt){
    if (kt + 1 < NKT) stage(kt + 1, smem + (cur ^ 1) * LDS_HALF);   // issue, don't wait
    unsigned short* lA = smem + cur * LDS_HALF;
    unsigned short* lB = lA + 8192;
#pragma unroll
    for (int kk = 0; kk < 2; ++kk){
      bf16x8 af[4], bfr[3];
#pragma unroll
      for (int mi = 0; mi < 4; ++mi){
        int row = wm * 64 + mi * 16 + lr;
        int ch  = (kk * 4 + lg) ^ (row & 7);
        af[mi] = *(const bf16x8*)(lA + row * 64 + ch * 8);
      }
#pragma unroll
      for (int j = 0; j < 3; ++j){                   // j = gate (f,i,h)
        int row = j * 64 + wn * 16 + lr;
        int ch  = (kk * 4 + lg) ^ (row & 7);
        bfr[j] = *(const bf16x8*)(lB + row * 64 + ch * 8);
      }
#pragma unroll
      for (int mi = 0; mi < 4; ++mi)
#pragma unroll
        for (int j = 0; j < 3; ++j)
          acc[mi][j] = __builtin_amdgcn_mfma_f32_16x16x32_bf16(af[mi], bfr[j], acc[mi][j], 0, 0, 0);
    }
    __syncthreads();   // vmcnt(0) drain lands AFTER compute hid the load latency
    cur ^= 1;
  }
  gate_epilogue3(acc, m0, c0, wm, wn, lr, lg, bfb, bib, bhb, Fw, Vw);
}

// ============ fallback GEMM (small ws): single-buffered, A converted in-loop ============
__launch_bounds__(512, 2)
__global__ void gemm_slow(const float* __restrict__ X, const unsigned short* __restrict__ Bm,
                          const float* __restrict__ bfb, const float* __restrict__ bib,
                          const float* __restrict__ bhb,
                          float* __restrict__ Fw, float* __restrict__ Vw){
  __shared__ unsigned short smem[LDS_HALF];
  unsigned short* lA = smem;
  unsigned short* lB = smem + 8192;
  const int tid = threadIdx.x, wid = tid >> 6, lane = tid & 63;
  const int m0 = blockIdx.x * BM, c0 = blockIdx.y * BCH;
  const int wm = wid >> 2, wn = wid & 3, lr = lane & 15, lg = lane >> 4;

  const unsigned short* bS[3];
#pragma unroll
  for (int q = 0; q < 3; ++q){
    int ci = q * 512 + tid, row = ci >> 3, cp = ci & 7;
    bS[q] = Bm + (size_t)((row >> 6) * 512 + c0 + (row & 63)) * KS + cp * 8;
  }
  unsigned short* bD0 = lB + (size_t)(tid & ~63) * 8;

  f32x4 acc[4][3];
#pragma unroll
  for (int a = 0; a < 4; ++a)
#pragma unroll
    for (int b = 0; b < 3; ++b) acc[a][b] = {0.f, 0.f, 0.f, 0.f};

  for (int kt = 0; kt < NKT; ++kt){
    const bool losec = (kt >= 8 && kt < 16);
    const int  ko    = (kt < 8 ? kt : (kt < 16 ? kt - 8 : kt - 16)) * 64;
    const int  boff  = (kt < 8 ? kt : kt - 8) * 64;
    if (kt) __syncthreads();
#pragma unroll
    for (int q = 0; q < 2; ++q){
      int ci = q * 512 + tid, row = ci >> 3, kc = ci & 7;
      const float* src = X + (size_t)(m0 + row) * DIN + ko + kc * 8;
      float4 xa = *(const float4*)src;
      float4 xb = *(const float4*)(src + 4);
      float xs[8] = {xa.x, xa.y, xa.z, xa.w, xb.x, xb.y, xb.z, xb.w};
      unsigned short hs[8];
#pragma unroll
      for (int e = 0; e < 8; ++e){
        unsigned short h = f2bf_rne(xs[e]);
        hs[e] = losec ? f2bf_rne(xs[e] - bf2f(h)) : h;
      }
      uint4 pk;
      pk.x = hs[0] | ((unsigned)hs[1] << 16); pk.y = hs[2] | ((unsigned)hs[3] << 16);
      pk.z = hs[4] | ((unsigned)hs[5] << 16); pk.w = hs[6] | ((unsigned)hs[7] << 16);
      *(uint4*)(lA + row * 64 + ((kc ^ (row & 7)) * 8)) = pk;
    }
#pragma unroll
    for (int q = 0; q < 3; ++q) gld16(bS[q] + boff, bD0 + q * 4096);
    __syncthreads();
#pragma unroll
    for (int kk = 0; kk < 2; ++kk){
      bf16x8 af[4], bfr[3];
#pragma unroll
      for (int mi = 0; mi < 4; ++mi){
        int row = wm * 64 + mi * 16 + lr;
        int ch  = (kk * 4 + lg) ^ (row & 7);
        af[mi] = *(const bf16x8*)(lA + row * 64 + ch * 8);
      }
#pragma unroll
      for (int j = 0; j < 3; ++j){
        int row = j * 64 + wn * 16 + lr;
        int ch  = (kk * 4 + lg) ^ (row & 7);
        bfr[j] = *(const bf16x8*)(lB + row * 64 + ch * 8);
      }
#pragma unroll
      for (int mi = 0; mi < 4; ++mi)
#pragma unroll
        for (int j = 0; j < 3; ++j)
          acc[mi][j] = __builtin_amdgcn_mfma_f32_16x16x32_bf16(af[mi], bfr[j], acc[mi][j], 0, 0, 0);
    }
  }
  gate_epilogue3(acc, m0, c0, wm, wn, lr, lg, bfb, bib, bhb, Fw, Vw);
}

// ============ scan phase A: per-chunk composition, float4 x 4 channels/thread ============
__global__ void scan_chunks(const float* __restrict__ Fw, const float* __restrict__ Vw,
                            float2* __restrict__ S){
  int bx = blockIdx.x;
  int chunk = bx >> 2, b = bx & 3;
  int ch4 = threadIdx.x * 4;
  size_t base = ((size_t)(b * T_SEQ + chunk * CHUNK_L)) * DH + ch4;
  float4 Fc = make_float4(1.f, 1.f, 1.f, 1.f);
  float4 Vc = make_float4(0.f, 0.f, 0.f, 0.f);
#pragma unroll 8
  for (int t = 0; t < CHUNK_L; ++t){
    float4 f = *(const float4*)(Fw + base + (size_t)t * DH);
    float4 v = *(const float4*)(Vw + base + (size_t)t * DH);
    Fc.x *= f.x; Fc.y *= f.y; Fc.z *= f.z; Fc.w *= f.w;
    Vc.x = fmaf(f.x, Vc.x, v.x); Vc.y = fmaf(f.y, Vc.y, v.y);
    Vc.z = fmaf(f.z, Vc.z, v.z); Vc.w = fmaf(f.w, Vc.w, v.w);
  }
  float2* s = S + (size_t)chunk * NCH_TOT + b * DH + ch4;
  s[0] = make_float2(Fc.x, Vc.x);
  s[1] = make_float2(Fc.y, Vc.y);
  s[2] = make_float2(Fc.z, Vc.z);
  s[3] = make_float2(Fc.w, Vc.w);
}

// ============ scan phase B: carry; seed = g(h0) ============
__global__ void scan_carry(const float2* __restrict__ S, const float* __restrict__ h0,
                           float* __restrict__ Hs){
  int cg = blockIdx.x * 256 + threadIdx.x;
  float hv = h0[cg];
  float h = (hv >= 0.f) ? (hv + 0.5f) : (1.f / (1.f + expf(-hv)));
  float2 s = S[cg];
#pragma unroll 16
  for (int k = 0; k < NCHUNK; ++k){
    float2 snext = (k + 1 < NCHUNK) ? S[(k + 1) * NCH_TOT + cg] : make_float2(0.f, 0.f);
    Hs[k * NCH_TOT + cg] = h;
    h = fmaf(s.x, h, s.y);
    s = snext;
  }
}

// ============ scan phase C: replay + output (V in d_out, in-place) ============
__global__ void scan_apply(const float* __restrict__ Fw, const float* Vw,
                           const float* __restrict__ Hs, float* out){
  int bx = blockIdx.x;
  int chunk = bx >> 2, b = bx & 3;
  int ch4 = threadIdx.x * 4;
  float4 h = *(const float4*)(Hs + (size_t)chunk * NCH_TOT + b * DH + ch4);
  size_t base = ((size_t)(b * T_SEQ + chunk * CHUNK_L)) * DH + ch4;
#pragma unroll 8
  for (int t = 0; t < CHUNK_L; ++t){
    size_t idx = base + (size_t)t * DH;
    float4 f = *(const float4*)(Fw + idx);
    float4 v = *(const float4*)(Vw + idx);
    h.x = fmaf(f.x, h.x, v.x); h.y = fmaf(f.y, h.y, v.y);
    h.z = fmaf(f.z, h.z, v.z); h.w = fmaf(f.w, h.w, v.w);
    *(float4*)(out + idx) = h;
  }
}

extern "C" void kernel_launch(void* const* d_in, const int* in_sizes, int n_in,
                              void* d_out, int out_size, void* d_ws, size_t ws_size,
                              hipStream_t stream){
  (void)in_sizes; (void)n_in; (void)out_size;
  const float* X  = (const float*)d_in[0];
  const float* h0 = (const float*)d_in[1];
  const float* Wf = (const float*)d_in[2];
  const float* bf = (const float*)d_in[3];
  const float* Wi = (const float*)d_in[4];
  const float* bi = (const float*)d_in[5];
  const float* Wh = (const float*)d_in[6];
  const float* bh = (const float*)d_in[7];

  constexpr size_t XA_B = (size_t)M_TOT * KS * 2;
  constexpr size_t F_B  = (size_t)M_TOT * DH * 4;
  constexpr size_t S_B  = (size_t)NCHUNK * NCH_TOT * 8;
  constexpr size_t H_B  = (size_t)NCHUNK * NCH_TOT * 4;
  constexpr size_t BMB  = (size_t)3 * 512 * KS * 2;
  const bool fast = ws_size >= XA_B + F_B + S_B + H_B + BMB;

  char* ws = (char*)d_ws;
  float* Vw  = (float*)d_out;
  float* out = (float*)d_out;

  if (fast){
    unsigned short* Xa  = (unsigned short*)ws;
    float*          Fw  = (float*)(ws + XA_B);
    float2*         S   = (float2*)(ws + XA_B + F_B);
    float*          Hs  = (float*)(ws + XA_B + F_B + S_B);
    unsigned short* Bmw = (unsigned short*)(ws + XA_B + F_B + S_B + H_B);
    aug_build <<<XB_BLOCKS + BM_BLOCKS, 256, 0, stream>>>(X, Wf, Wi, Wh, Xa, Bmw, 1);
    gemm_fast <<<GRID_WG, 512, 0, stream>>>(Xa, Bmw, bf, bi, bh, Fw, Vw);
    scan_chunks<<<256, 128, 0, stream>>>(Fw, Vw, S);
    scan_carry <<<8, 256, 0, stream>>>(S, h0, Hs);
    scan_apply <<<256, 128, 0, stream>>>(Fw, Vw, Hs, out);
  } else {
    float*          Fw  = (float*)ws;
    float2*         S   = (float2*)(ws + F_B);
    float*          Hs  = (float*)(ws + F_B + S_B);
    unsigned short* Bmw = (unsigned short*)(ws + F_B + S_B + H_B);
    aug_build <<<BM_BLOCKS, 256, 0, stream>>>(X, Wf, Wi, Wh, nullptr, Bmw, 0);
    gemm_slow <<<dim3(M_TOT / BM, DH / BCH), 512, 0, stream>>>(X, Bmw, bf, bi, bh, Fw, Vw);
    scan_chunks<<<256, 128, 0, stream>>>(Fw, Vw, S);
    scan_carry <<<8, 256, 0, stream>>>(S, h0, Hs);
    scan_apply <<<256, 128, 0, stream>>>(Fw, Vw, Hs, out);
  }
}

// Round 10
// 411.260 us; speedup vs baseline: 1.2144x; 1.0930x over previous
//
#include <hip/hip_runtime.h>
#include <hip/hip_bf16.h>
#include <stdint.h>

#define T_SEQ 8192
#define BB    4
#define DH    512
#define DIN   512
#define M_TOT (BB*T_SEQ)          // 32768
#define BM    128
#define BCH   64                  // channels per block -> 3*BCH = 192 B-rows in LDS
#define BK    64
#define NKT   24                  // K_aug = 1536 (A=[hi,lo,hi] x B=[hi,hi,lo])
#define KS    1024                // stored ushorts per row: [hi(512) | lo(512)]
#define CHUNK_L 128
#define NCHUNK  64
#define NCH_TOT (BB*DH)           // 2048
#define GRID_WG 2048              // (M_TOT/BM) * (DH/BCH)
#define LDS_HALF 20480            // ushorts per buffer: A 8192 + B 12288 (40 KiB)

#define XB_BLOCKS 8192
#define BM_BLOCKS 384

typedef __attribute__((ext_vector_type(4))) float f32x4;
typedef __attribute__((ext_vector_type(8))) short bf16x8;

__device__ __forceinline__ unsigned short f2bf_rne(float x){
  unsigned u = __float_as_uint(x);
  return (unsigned short)((u + 0x7FFFu + ((u >> 16) & 1u)) >> 16);
}
__device__ __forceinline__ float bf2f(unsigned short h){
  return __uint_as_float(((unsigned)h) << 16);
}
__device__ __forceinline__ void gld16(const void* g, void* l){
  __builtin_amdgcn_global_load_lds((const __attribute__((address_space(1))) unsigned*)g,
                                   (__attribute__((address_space(3))) unsigned*)l, 16, 0, 0);
}

__device__ __forceinline__ void split8_store(const float* src, unsigned short* dhi){
  float4 a = *(const float4*)src;
  float4 b = *(const float4*)(src + 4);
  float xs[8] = {a.x, a.y, a.z, a.w, b.x, b.y, b.z, b.w};
  unsigned short hi[8], lo[8];
#pragma unroll
  for (int e = 0; e < 8; ++e){
    hi[e] = f2bf_rne(xs[e]);
    lo[e] = f2bf_rne(xs[e] - bf2f(hi[e]));
  }
  uint4 ph, pl;
  ph.x = hi[0] | ((unsigned)hi[1] << 16); ph.y = hi[2] | ((unsigned)hi[3] << 16);
  ph.z = hi[4] | ((unsigned)hi[5] << 16); ph.w = hi[6] | ((unsigned)hi[7] << 16);
  pl.x = lo[0] | ((unsigned)lo[1] << 16); pl.y = lo[2] | ((unsigned)lo[3] << 16);
  pl.z = lo[4] | ((unsigned)lo[5] << 16); pl.w = lo[6] | ((unsigned)lo[7] << 16);
  *(uint4*)dhi = ph;
  *(uint4*)(dhi + 512) = pl;
}

// ============ merged build (pre-swizzled: phys chunk = clog ^ (row&7)) ============
__global__ void aug_build(const float* __restrict__ X,
                          const float* __restrict__ Wf, const float* __restrict__ Wi,
                          const float* __restrict__ Wh,
                          unsigned short* __restrict__ Xa, unsigned short* __restrict__ Bm,
                          int with_xa){
  int bx = blockIdx.x;
  if (with_xa && bx < XB_BLOCKS){
    int g = bx * 256 + threadIdx.x;
    int row  = g >> 6;
    int tile = (g >> 3) & 7;
    int clog = g & 7;
    int cphys = clog ^ (row & 7);
    split8_store(X + (size_t)row * DIN + tile * 64 + clog * 8,
                 Xa + (size_t)row * KS + tile * 64 + cphys * 8);
  } else {
    int g = (bx - (with_xa ? XB_BLOCKS : 0)) * 256 + threadIdx.x;
    int gate = g >> 15;
    int ch   = (g >> 6) & 511;
    int tile = (g >> 3) & 7;
    int clog = g & 7;
    const float* W = (gate == 0) ? Wf : ((gate == 1) ? Wi : Wh);
    int cphys = clog ^ (ch & 7);
    split8_store(W + (size_t)ch * DIN + tile * 64 + clog * 8,
                 Bm + (size_t)(gate * 512 + ch) * KS + tile * 64 + cphys * 8);
  }
}

// gates from pre-activations
__device__ __forceinline__ void gates_eval(float fp, float ip, float hp, float& fg, float& v){
  float zf = -fp, zi = -ip;
  float spf = fmaxf(zf, 0.f) + log1pf(expf(-fabsf(zf)));   // softplus(-f_pre)
  float spi = fmaxf(zi, 0.f) + log1pf(expf(-fabsf(zi)));   // softplus(-i_pre)
  float ef  = expf(spf - spi);                              // exp(diff)
  fg = 1.f / (1.f + ef);                                    // forget = sigmoid(-diff)
  float g = (hp >= 0.f) ? (hp + 0.5f) : (1.f / (1.f + expf(-hp)));
  v = (1.f - fg) * g;                                       // i_t * g_t
}

// ============ epilogue (fallback): bias + gates -> F, V ============
__device__ __forceinline__ void gate_epilogue3(const f32x4 acc[4][3], int m0, int c0,
                                               int wm, int wn, int lr, int lg,
                                               const float* bfb, const float* bib, const float* bhb,
                                               float* Fw, float* Vw){
  int chan = c0 + wn * 16 + lr;
  float bfv = bfb[chan], biv = bib[chan], bhv = bhb[chan];
#pragma unroll
  for (int mi = 0; mi < 4; ++mi){
#pragma unroll
    for (int r = 0; r < 4; ++r){
      int bt = m0 + wm * 64 + mi * 16 + lg * 4 + r;
      float fg, v;
      gates_eval(acc[mi][0][r] + bfv, acc[mi][1][r] + biv, acc[mi][2][r] + bhv, fg, v);
      size_t idx = (size_t)bt * DH + chan;
      Fw[idx] = fg;
      Vw[idx] = v;
    }
  }
}

// ============ fast GEMM: 2-phase dbuf, unroll-2 static buffers, fused chunk-scan ============
// VALU fix (R9 PMC: VALUBusy 71% > MfmaUtil 28%): loop unrolled by 2 so both LDS buffer
// pointers are compile-time -> all 14 swizzled ds_read address chains hoist out of the loop.
// Fused scan: block tile = exactly one (chunk=128 t) x (64 chan) -> chunk summary computed
// block-locally (LDS segmented affine-compose), eliminating the scan_chunks pass.
__launch_bounds__(512, 4)
__global__ void gemm_fast(const unsigned short* __restrict__ Xa, const unsigned short* __restrict__ Bm,
                          const float* __restrict__ bfb, const float* __restrict__ bib,
                          const float* __restrict__ bhb,
                          float* __restrict__ Fw, float* __restrict__ Vw,
                          float2* __restrict__ S){
  __shared__ unsigned short smem[2 * LDS_HALF];      // 80 KiB
  const int tid = threadIdx.x, wid = tid >> 6, lane = tid & 63;
  // bijective chunked XCD swizzle (GRID_WG % 8 == 0)
  const int wg = (blockIdx.x & 7) * (GRID_WG / 8) + (blockIdx.x >> 3);
  const int m0 = (wg >> 3) * BM, c0 = (wg & 7) * BCH;
  const int wm = wid >> 2, wn = wid & 3, lr = lane & 15, lg = lane >> 4;

  const unsigned short* aS0 = Xa + (size_t)(m0 + (tid >> 3)) * KS + (tid & 7) * 8;
  const unsigned short* aS1 = aS0 + (size_t)64 * KS;
  const unsigned short* bS[3];
#pragma unroll
  for (int q = 0; q < 3; ++q){
    int ci = q * 512 + tid, row = ci >> 3, cp = ci & 7;   // row in [0,192)
    bS[q] = Bm + (size_t)((row >> 6) * 512 + c0 + (row & 63)) * KS + cp * 8;
  }
  const int ldst = (tid & ~63) * 8;                  // wave-uniform LDS base (m104)
  unsigned short* buf0 = smem;
  unsigned short* buf1 = smem + LDS_HALF;

  f32x4 acc[4][3];
#pragma unroll
  for (int a = 0; a < 4; ++a)
#pragma unroll
    for (int b = 0; b < 3; ++b) acc[a][b] = {0.f, 0.f, 0.f, 0.f};

  auto stage = [&](int kt, unsigned short* buf){     // A=[hi,lo,hi], B=[hi,hi,lo]
    const int aoff = (kt < 16 ? kt : kt - 16) * 64;
    const int boff = (kt < 8  ? kt : kt - 8 ) * 64;
    unsigned short* aD = buf + ldst;
    gld16(aS0 + aoff, aD);
    gld16(aS1 + aoff, aD + 4096);
    unsigned short* bD = buf + 8192 + ldst;
#pragma unroll
    for (int q = 0; q < 3; ++q) gld16(bS[q] + boff, bD + q * 4096);
  };

  auto compute = [&](const unsigned short* lA){      // static buffer -> hoisted addresses
    const unsigned short* lB = lA + 8192;
#pragma unroll
    for (int kk = 0; kk < 2; ++kk){
      bf16x8 af[4], bfr[3];
#pragma unroll
      for (int mi = 0; mi < 4; ++mi){
        int row = wm * 64 + mi * 16 + lr;
        int ch  = (kk * 4 + lg) ^ (row & 7);
        af[mi] = *(const bf16x8*)(lA + row * 64 + ch * 8);
      }
#pragma unroll
      for (int j = 0; j < 3; ++j){
        int row = j * 64 + wn * 16 + lr;
        int ch  = (kk * 4 + lg) ^ (row & 7);
        bfr[j] = *(const bf16x8*)(lB + row * 64 + ch * 8);
      }
      __builtin_amdgcn_s_setprio(1);
#pragma unroll
      for (int mi = 0; mi < 4; ++mi)
#pragma unroll
        for (int j = 0; j < 3; ++j)
          acc[mi][j] = __builtin_amdgcn_mfma_f32_16x16x32_bf16(af[mi], bfr[j], acc[mi][j], 0, 0, 0);
      __builtin_amdgcn_s_setprio(0);
    }
  };

  stage(0, buf0);
  __syncthreads();
  for (int it = 0; it < NKT / 2; ++it){
    stage(2 * it + 1, buf1);                 // issue, don't wait
    compute(buf0);
    __syncthreads();
    if (2 * it + 2 < NKT) stage(2 * it + 2, buf0);
    compute(buf1);
    __syncthreads();
  }

  // ---- epilogue: gates -> F,V global; 4-step affine pairs -> LDS (t-order = r-order) ----
  float2* pairs = (float2*)smem;                     // [64 chan][32 pairs]  16 KiB
  float2* part4 = ((float2*)smem) + 64 * 32;         // [64 chan][4]          2 KiB
  const int chan_l = wn * 16 + lr;
  const int chan   = c0 + chan_l;
  {
    float bfv = bfb[chan], biv = bib[chan], bhv = bhb[chan];
#pragma unroll
    for (int mi = 0; mi < 4; ++mi){
      float F4 = 1.f, V4 = 0.f;
#pragma unroll
      for (int r = 0; r < 4; ++r){
        int bt = m0 + wm * 64 + mi * 16 + lg * 4 + r;
        float fg, v;
        gates_eval(acc[mi][0][r] + bfv, acc[mi][1][r] + biv, acc[mi][2][r] + bhv, fg, v);
        size_t idx = (size_t)bt * DH + chan;
        Fw[idx] = fg;
        Vw[idx] = v;
        F4 = fg * F4;                 // compose ascending t
        V4 = fmaf(fg, V4, v);
      }
      pairs[chan_l * 32 + wm * 16 + mi * 4 + lg] = make_float2(F4, V4);   // p = t>>2
    }
  }
  __syncthreads();
  if (tid < 256){                                    // 4 threads/chan: compose 8 pairs each
    int cl = tid >> 2, q = tid & 3;
    float F = 1.f, V = 0.f;
#pragma unroll
    for (int i = 0; i < 8; ++i){
      float2 pr = pairs[cl * 32 + q * 8 + i];
      F = pr.x * F;
      V = fmaf(pr.x, V, pr.y);
    }
    part4[cl * 4 + q] = make_float2(F, V);
  }
  __syncthreads();
  if (tid < 64){                                     // final 4-way compose -> chunk summary
    float F = 1.f, V = 0.f;
#pragma unroll
    for (int i = 0; i < 4; ++i){
      float2 pr = part4[tid * 4 + i];
      F = pr.x * F;
      V = fmaf(pr.x, V, pr.y);
    }
    int b     = m0 >> 13;                            // m0 / 8192
    int chunk = (m0 & 8191) >> 7;                    // (m0 % 8192) / 128
    S[chunk * NCH_TOT + b * DH + c0 + tid] = make_float2(F, V);
  }
}

// ============ fallback GEMM (small ws): single-buffered, A converted in-loop ============
__launch_bounds__(512, 2)
__global__ void gemm_slow(const float* __restrict__ X, const unsigned short* __restrict__ Bm,
                          const float* __restrict__ bfb, const float* __restrict__ bib,
                          const float* __restrict__ bhb,
                          float* __restrict__ Fw, float* __restrict__ Vw){
  __shared__ unsigned short smem[LDS_HALF];
  unsigned short* lA = smem;
  unsigned short* lB = smem + 8192;
  const int tid = threadIdx.x, wid = tid >> 6, lane = tid & 63;
  const int m0 = blockIdx.x * BM, c0 = blockIdx.y * BCH;
  const int wm = wid >> 2, wn = wid & 3, lr = lane & 15, lg = lane >> 4;

  const unsigned short* bS[3];
#pragma unroll
  for (int q = 0; q < 3; ++q){
    int ci = q * 512 + tid, row = ci >> 3, cp = ci & 7;
    bS[q] = Bm + (size_t)((row >> 6) * 512 + c0 + (row & 63)) * KS + cp * 8;
  }
  unsigned short* bD0 = lB + (size_t)(tid & ~63) * 8;

  f32x4 acc[4][3];
#pragma unroll
  for (int a = 0; a < 4; ++a)
#pragma unroll
    for (int b = 0; b < 3; ++b) acc[a][b] = {0.f, 0.f, 0.f, 0.f};

  for (int kt = 0; kt < NKT; ++kt){
    const bool losec = (kt >= 8 && kt < 16);
    const int  ko    = (kt < 8 ? kt : (kt < 16 ? kt - 8 : kt - 16)) * 64;
    const int  boff  = (kt < 8 ? kt : kt - 8) * 64;
    if (kt) __syncthreads();
#pragma unroll
    for (int q = 0; q < 2; ++q){
      int ci = q * 512 + tid, row = ci >> 3, kc = ci & 7;
      const float* src = X + (size_t)(m0 + row) * DIN + ko + kc * 8;
      float4 xa = *(const float4*)src;
      float4 xb = *(const float4*)(src + 4);
      float xs[8] = {xa.x, xa.y, xa.z, xa.w, xb.x, xb.y, xb.z, xb.w};
      unsigned short hs[8];
#pragma unroll
      for (int e = 0; e < 8; ++e){
        unsigned short h = f2bf_rne(xs[e]);
        hs[e] = losec ? f2bf_rne(xs[e] - bf2f(h)) : h;
      }
      uint4 pk;
      pk.x = hs[0] | ((unsigned)hs[1] << 16); pk.y = hs[2] | ((unsigned)hs[3] << 16);
      pk.z = hs[4] | ((unsigned)hs[5] << 16); pk.w = hs[6] | ((unsigned)hs[7] << 16);
      *(uint4*)(lA + row * 64 + ((kc ^ (row & 7)) * 8)) = pk;
    }
#pragma unroll
    for (int q = 0; q < 3; ++q) gld16(bS[q] + boff, bD0 + q * 4096);
    __syncthreads();
#pragma unroll
    for (int kk = 0; kk < 2; ++kk){
      bf16x8 af[4], bfr[3];
#pragma unroll
      for (int mi = 0; mi < 4; ++mi){
        int row = wm * 64 + mi * 16 + lr;
        int ch  = (kk * 4 + lg) ^ (row & 7);
        af[mi] = *(const bf16x8*)(lA + row * 64 + ch * 8);
      }
#pragma unroll
      for (int j = 0; j < 3; ++j){
        int row = j * 64 + wn * 16 + lr;
        int ch  = (kk * 4 + lg) ^ (row & 7);
        bfr[j] = *(const bf16x8*)(lB + row * 64 + ch * 8);
      }
#pragma unroll
      for (int mi = 0; mi < 4; ++mi)
#pragma unroll
        for (int j = 0; j < 3; ++j)
          acc[mi][j] = __builtin_amdgcn_mfma_f32_16x16x32_bf16(af[mi], bfr[j], acc[mi][j], 0, 0, 0);
    }
  }
  gate_epilogue3(acc, m0, c0, wm, wn, lr, lg, bfb, bib, bhb, Fw, Vw);
}

// ============ scan phase A (fallback path only): per-chunk composition ============
__global__ void scan_chunks(const float* __restrict__ Fw, const float* __restrict__ Vw,
                            float2* __restrict__ S){
  int bx = blockIdx.x;
  int chunk = bx >> 2, b = bx & 3;
  int ch4 = threadIdx.x * 4;
  size_t base = ((size_t)(b * T_SEQ + chunk * CHUNK_L)) * DH + ch4;
  float4 Fc = make_float4(1.f, 1.f, 1.f, 1.f);
  float4 Vc = make_float4(0.f, 0.f, 0.f, 0.f);
#pragma unroll 8
  for (int t = 0; t < CHUNK_L; ++t){
    float4 f = *(const float4*)(Fw + base + (size_t)t * DH);
    float4 v = *(const float4*)(Vw + base + (size_t)t * DH);
    Fc.x *= f.x; Fc.y *= f.y; Fc.z *= f.z; Fc.w *= f.w;
    Vc.x = fmaf(f.x, Vc.x, v.x); Vc.y = fmaf(f.y, Vc.y, v.y);
    Vc.z = fmaf(f.z, Vc.z, v.z); Vc.w = fmaf(f.w, Vc.w, v.w);
  }
  float2* s = S + (size_t)chunk * NCH_TOT + b * DH + ch4;
  s[0] = make_float2(Fc.x, Vc.x);
  s[1] = make_float2(Fc.y, Vc.y);
  s[2] = make_float2(Fc.z, Vc.z);
  s[3] = make_float2(Fc.w, Vc.w);
}

// ============ scan phase B: carry; seed = g(h0) ============
__global__ void scan_carry(const float2* __restrict__ S, const float* __restrict__ h0,
                           float* __restrict__ Hs){
  int cg = blockIdx.x * 256 + threadIdx.x;
  float hv = h0[cg];
  float h = (hv >= 0.f) ? (hv + 0.5f) : (1.f / (1.f + expf(-hv)));
  float2 s = S[cg];
#pragma unroll 16
  for (int k = 0; k < NCHUNK; ++k){
    float2 snext = (k + 1 < NCHUNK) ? S[(k + 1) * NCH_TOT + cg] : make_float2(0.f, 0.f);
    Hs[k * NCH_TOT + cg] = h;
    h = fmaf(s.x, h, s.y);
    s = snext;
  }
}

// ============ scan phase C: replay + output (V in d_out, in-place) ============
__global__ void scan_apply(const float* __restrict__ Fw, const float* Vw,
                           const float* __restrict__ Hs, float* out){
  int bx = blockIdx.x;
  int chunk = bx >> 2, b = bx & 3;
  int ch4 = threadIdx.x * 4;
  float4 h = *(const float4*)(Hs + (size_t)chunk * NCH_TOT + b * DH + ch4);
  size_t base = ((size_t)(b * T_SEQ + chunk * CHUNK_L)) * DH + ch4;
#pragma unroll 8
  for (int t = 0; t < CHUNK_L; ++t){
    size_t idx = base + (size_t)t * DH;
    float4 f = *(const float4*)(Fw + idx);
    float4 v = *(const float4*)(Vw + idx);
    h.x = fmaf(f.x, h.x, v.x); h.y = fmaf(f.y, h.y, v.y);
    h.z = fmaf(f.z, h.z, v.z); h.w = fmaf(f.w, h.w, v.w);
    *(float4*)(out + idx) = h;
  }
}

extern "C" void kernel_launch(void* const* d_in, const int* in_sizes, int n_in,
                              void* d_out, int out_size, void* d_ws, size_t ws_size,
                              hipStream_t stream){
  (void)in_sizes; (void)n_in; (void)out_size;
  const float* X  = (const float*)d_in[0];
  const float* h0 = (const float*)d_in[1];
  const float* Wf = (const float*)d_in[2];
  const float* bf = (const float*)d_in[3];
  const float* Wi = (const float*)d_in[4];
  const float* bi = (const float*)d_in[5];
  const float* Wh = (const float*)d_in[6];
  const float* bh = (const float*)d_in[7];

  constexpr size_t XA_B = (size_t)M_TOT * KS * 2;
  constexpr size_t F_B  = (size_t)M_TOT * DH * 4;
  constexpr size_t S_B  = (size_t)NCHUNK * NCH_TOT * 8;
  constexpr size_t H_B  = (size_t)NCHUNK * NCH_TOT * 4;
  constexpr size_t BMB  = (size_t)3 * 512 * KS * 2;
  const bool fast = ws_size >= XA_B + F_B + S_B + H_B + BMB;

  char* ws = (char*)d_ws;
  float* Vw  = (float*)d_out;
  float* out = (float*)d_out;

  if (fast){
    unsigned short* Xa  = (unsigned short*)ws;
    float*          Fw  = (float*)(ws + XA_B);
    float2*         S   = (float2*)(ws + XA_B + F_B);
    float*          Hs  = (float*)(ws + XA_B + F_B + S_B);
    unsigned short* Bmw = (unsigned short*)(ws + XA_B + F_B + S_B + H_B);
    aug_build <<<XB_BLOCKS + BM_BLOCKS, 256, 0, stream>>>(X, Wf, Wi, Wh, Xa, Bmw, 1);
    gemm_fast <<<GRID_WG, 512, 0, stream>>>(Xa, Bmw, bf, bi, bh, Fw, Vw, S);
    scan_carry <<<8, 256, 0, stream>>>(S, h0, Hs);
    scan_apply <<<256, 128, 0, stream>>>(Fw, Vw, Hs, out);
  } else {
    float*          Fw  = (float*)ws;
    float2*         S   = (float2*)(ws + F_B);
    float*          Hs  = (float*)(ws + F_B + S_B);
    unsigned short* Bmw = (unsigned short*)(ws + F_B + S_B + H_B);
    aug_build <<<BM_BLOCKS, 256, 0, stream>>>(X, Wf, Wi, Wh, nullptr, Bmw, 0);
    gemm_slow <<<dim3(M_TOT / BM, DH / BCH), 512, 0, stream>>>(X, Bmw, bf, bi, bh, Fw, Vw);
    scan_chunks<<<256, 128, 0, stream>>>(Fw, Vw, S);
    scan_carry <<<8, 256, 0, stream>>>(S, h0, Hs);
    scan_apply <<<256, 128, 0, stream>>>(Fw, Vw, Hs, out);
  }
}

// Round 11
// 376.062 us; speedup vs baseline: 1.3281x; 1.0936x over previous
//
#include <hip/hip_runtime.h>
#include <hip/hip_bf16.h>
#include <stdint.h>

#define T_SEQ 8192
#define BB    4
#define DH    512
#define DIN   512
#define M_TOT (BB*T_SEQ)          // 32768
#define BM    128
#define BCH   64                  // channels per block -> 3*BCH = 192 B-rows in LDS
#define BK    64
#define NKT   16                  // K_aug = 1024 (bf16x2: A=[hi,lo] x B=[hi,hi])
#define KS    1024                // stored ushorts per row: [hi(512) | lo(512)]
#define CHUNK_L 128
#define NCHUNK  64
#define NCH_TOT (BB*DH)           // 2048
#define GRID_WG 2048              // (M_TOT/BM) * (DH/BCH)
#define LDS_HALF 20480            // ushorts per buffer: A 8192 + B 12288 (40 KiB)

#define XB_BLOCKS 8192
#define BM_BLOCKS 384

typedef __attribute__((ext_vector_type(4))) float f32x4;
typedef __attribute__((ext_vector_type(8))) short bf16x8;

__device__ __forceinline__ unsigned short f2bf_rne(float x){
  unsigned u = __float_as_uint(x);
  return (unsigned short)((u + 0x7FFFu + ((u >> 16) & 1u)) >> 16);
}
__device__ __forceinline__ float bf2f(unsigned short h){
  return __uint_as_float(((unsigned)h) << 16);
}
__device__ __forceinline__ void gld16(const void* g, void* l){
  __builtin_amdgcn_global_load_lds((const __attribute__((address_space(1))) unsigned*)g,
                                   (__attribute__((address_space(3))) unsigned*)l, 16, 0, 0);
}

__device__ __forceinline__ void split8_store(const float* src, unsigned short* dhi){
  float4 a = *(const float4*)src;
  float4 b = *(const float4*)(src + 4);
  float xs[8] = {a.x, a.y, a.z, a.w, b.x, b.y, b.z, b.w};
  unsigned short hi[8], lo[8];
#pragma unroll
  for (int e = 0; e < 8; ++e){
    hi[e] = f2bf_rne(xs[e]);
    lo[e] = f2bf_rne(xs[e] - bf2f(hi[e]));
  }
  uint4 ph, pl;
  ph.x = hi[0] | ((unsigned)hi[1] << 16); ph.y = hi[2] | ((unsigned)hi[3] << 16);
  ph.z = hi[4] | ((unsigned)hi[5] << 16); ph.w = hi[6] | ((unsigned)hi[7] << 16);
  pl.x = lo[0] | ((unsigned)lo[1] << 16); pl.y = lo[2] | ((unsigned)lo[3] << 16);
  pl.z = lo[4] | ((unsigned)lo[5] << 16); pl.w = lo[6] | ((unsigned)lo[7] << 16);
  *(uint4*)dhi = ph;
  *(uint4*)(dhi + 512) = pl;
}

// ============ merged build (pre-swizzled: phys chunk = clog ^ (row&7)) ============
__global__ void aug_build(const float* __restrict__ X,
                          const float* __restrict__ Wf, const float* __restrict__ Wi,
                          const float* __restrict__ Wh,
                          unsigned short* __restrict__ Xa, unsigned short* __restrict__ Bm,
                          int with_xa){
  int bx = blockIdx.x;
  if (with_xa && bx < XB_BLOCKS){
    int g = bx * 256 + threadIdx.x;
    int row  = g >> 6;
    int tile = (g >> 3) & 7;
    int clog = g & 7;
    int cphys = clog ^ (row & 7);
    split8_store(X + (size_t)row * DIN + tile * 64 + clog * 8,
                 Xa + (size_t)row * KS + tile * 64 + cphys * 8);
  } else {
    int g = (bx - (with_xa ? XB_BLOCKS : 0)) * 256 + threadIdx.x;
    int gate = g >> 15;
    int ch   = (g >> 6) & 511;
    int tile = (g >> 3) & 7;
    int clog = g & 7;
    const float* W = (gate == 0) ? Wf : ((gate == 1) ? Wi : Wh);
    int cphys = clog ^ (ch & 7);
    split8_store(W + (size_t)ch * DIN + tile * 64 + clog * 8,
                 Bm + (size_t)(gate * 512 + ch) * KS + tile * 64 + cphys * 8);
  }
}

// gates from pre-activations
__device__ __forceinline__ void gates_eval(float fp, float ip, float hp, float& fg, float& v){
  float zf = -fp, zi = -ip;
  float spf = fmaxf(zf, 0.f) + log1pf(expf(-fabsf(zf)));   // softplus(-f_pre)
  float spi = fmaxf(zi, 0.f) + log1pf(expf(-fabsf(zi)));   // softplus(-i_pre)
  float ef  = expf(spf - spi);                              // exp(diff)
  fg = 1.f / (1.f + ef);                                    // forget = sigmoid(-diff)
  float g = (hp >= 0.f) ? (hp + 0.5f) : (1.f / (1.f + expf(-hp)));
  v = (1.f - fg) * g;                                       // i_t * g_t
}

// ============ epilogue (fallback): bias + gates -> F, V ============
__device__ __forceinline__ void gate_epilogue3(const f32x4 acc[4][3], int m0, int c0,
                                               int wm, int wn, int lr, int lg,
                                               const float* bfb, const float* bib, const float* bhb,
                                               float* Fw, float* Vw){
  int chan = c0 + wn * 16 + lr;
  float bfv = bfb[chan], biv = bib[chan], bhv = bhb[chan];
#pragma unroll
  for (int mi = 0; mi < 4; ++mi){
#pragma unroll
    for (int r = 0; r < 4; ++r){
      int bt = m0 + wm * 64 + mi * 16 + lg * 4 + r;
      float fg, v;
      gates_eval(acc[mi][0][r] + bfv, acc[mi][1][r] + biv, acc[mi][2][r] + bhv, fg, v);
      size_t idx = (size_t)bt * DH + chan;
      Fw[idx] = fg;
      Vw[idx] = v;
    }
  }
}

// ============ fast GEMM: bf16x2 (K_aug=1024), 2-phase dbuf, fused chunk-scan ============
// bf16x2: A walks [hi(512)|lo(512)] (aoff = kt*64), B re-reads hi twice (boff = (kt&7)*64).
// Product = fp32(x) . bf16(W); error = x.(W - bf16W) ~ 4e-4 in pre-acts (<< absmax 0.0156).
// Epilogue chunk-compose uses pairs[32][65] (2-way-free writes, R10's 4.3M conflicts fixed).
__launch_bounds__(512, 4)
__global__ void gemm_fast(const unsigned short* __restrict__ Xa, const unsigned short* __restrict__ Bm,
                          const float* __restrict__ bfb, const float* __restrict__ bib,
                          const float* __restrict__ bhb,
                          float* __restrict__ Fw, float* __restrict__ Vw,
                          float2* __restrict__ S){
  __shared__ unsigned short smem[2 * LDS_HALF];      // 80 KiB
  const int tid = threadIdx.x, wid = tid >> 6, lane = tid & 63;
  // bijective chunked XCD swizzle (GRID_WG % 8 == 0)
  const int wg = (blockIdx.x & 7) * (GRID_WG / 8) + (blockIdx.x >> 3);
  const int m0 = (wg >> 3) * BM, c0 = (wg & 7) * BCH;
  const int wm = wid >> 2, wn = wid & 3, lr = lane & 15, lg = lane >> 4;

  const unsigned short* aS0 = Xa + (size_t)(m0 + (tid >> 3)) * KS + (tid & 7) * 8;
  const unsigned short* aS1 = aS0 + (size_t)64 * KS;
  const unsigned short* bS[3];
#pragma unroll
  for (int q = 0; q < 3; ++q){
    int ci = q * 512 + tid, row = ci >> 3, cp = ci & 7;   // row in [0,192)
    bS[q] = Bm + (size_t)((row >> 6) * 512 + c0 + (row & 63)) * KS + cp * 8;
  }
  const int ldst = (tid & ~63) * 8;                  // wave-uniform LDS base (m104)
  unsigned short* buf0 = smem;
  unsigned short* buf1 = smem + LDS_HALF;

  f32x4 acc[4][3];
#pragma unroll
  for (int a = 0; a < 4; ++a)
#pragma unroll
    for (int b = 0; b < 3; ++b) acc[a][b] = {0.f, 0.f, 0.f, 0.f};

  auto stage = [&](int kt, unsigned short* buf){     // A=[hi,lo], B=[hi,hi]
    const int aoff = kt * 64;                        // walks full [hi|lo] row
    const int boff = (kt & 7) * 64;                  // hi section twice
    unsigned short* aD = buf + ldst;
    gld16(aS0 + aoff, aD);
    gld16(aS1 + aoff, aD + 4096);
    unsigned short* bD = buf + 8192 + ldst;
#pragma unroll
    for (int q = 0; q < 3; ++q) gld16(bS[q] + boff, bD + q * 4096);
  };

  auto compute = [&](const unsigned short* lA){      // static buffer -> hoisted addresses
    const unsigned short* lB = lA + 8192;
#pragma unroll
    for (int kk = 0; kk < 2; ++kk){
      bf16x8 af[4], bfr[3];
#pragma unroll
      for (int mi = 0; mi < 4; ++mi){
        int row = wm * 64 + mi * 16 + lr;
        int ch  = (kk * 4 + lg) ^ (row & 7);
        af[mi] = *(const bf16x8*)(lA + row * 64 + ch * 8);
      }
#pragma unroll
      for (int j = 0; j < 3; ++j){
        int row = j * 64 + wn * 16 + lr;
        int ch  = (kk * 4 + lg) ^ (row & 7);
        bfr[j] = *(const bf16x8*)(lB + row * 64 + ch * 8);
      }
      __builtin_amdgcn_s_setprio(1);
#pragma unroll
      for (int mi = 0; mi < 4; ++mi)
#pragma unroll
        for (int j = 0; j < 3; ++j)
          acc[mi][j] = __builtin_amdgcn_mfma_f32_16x16x32_bf16(af[mi], bfr[j], acc[mi][j], 0, 0, 0);
      __builtin_amdgcn_s_setprio(0);
    }
  };

  stage(0, buf0);
  __syncthreads();
  for (int it = 0; it < NKT / 2; ++it){
    stage(2 * it + 1, buf1);                 // issue, don't wait
    compute(buf0);
    __syncthreads();
    if (2 * it + 2 < NKT) stage(2 * it + 2, buf0);
    compute(buf1);
    __syncthreads();
  }

  // ---- epilogue: gates -> F,V global; 4-step affine pairs -> LDS [p][65] (t = 4p + r) ----
  float2* pairs = (float2*)smem;                     // [32][65] float2, ~16.6 KiB
  const int chan_l = wn * 16 + lr;
  const int chan   = c0 + chan_l;
  {
    float bfv = bfb[chan], biv = bib[chan], bhv = bhb[chan];
#pragma unroll
    for (int mi = 0; mi < 4; ++mi){
      float F4 = 1.f, V4 = 0.f;
#pragma unroll
      for (int r = 0; r < 4; ++r){
        int bt = m0 + wm * 64 + mi * 16 + lg * 4 + r;
        float fg, v;
        gates_eval(acc[mi][0][r] + bfv, acc[mi][1][r] + biv, acc[mi][2][r] + bhv, fg, v);
        size_t idx = (size_t)bt * DH + chan;
        Fw[idx] = fg;
        Vw[idx] = v;
        F4 = fg * F4;                 // compose ascending t
        V4 = fmaf(fg, V4, v);
      }
      pairs[(wm * 16 + mi * 4 + lg) * 65 + chan_l] = make_float2(F4, V4);
    }
  }
  __syncthreads();
  if (tid < 64){                                     // one wave: serial compose 32 pairs/chan
    float F = 1.f, V = 0.f;
#pragma unroll 8
    for (int p = 0; p < 32; ++p){
      float2 pr = pairs[p * 65 + tid];
      F = pr.x * F;
      V = fmaf(pr.x, V, pr.y);
    }
    int b     = m0 >> 13;                            // m0 / 8192
    int chunk = (m0 & 8191) >> 7;                    // (m0 % 8192) / 128
    S[chunk * NCH_TOT + b * DH + c0 + tid] = make_float2(F, V);
  }
}

// ============ fallback GEMM (small ws): single-buffered, A converted in-loop ============
__launch_bounds__(512, 2)
__global__ void gemm_slow(const float* __restrict__ X, const unsigned short* __restrict__ Bm,
                          const float* __restrict__ bfb, const float* __restrict__ bib,
                          const float* __restrict__ bhb,
                          float* __restrict__ Fw, float* __restrict__ Vw){
  __shared__ unsigned short smem[LDS_HALF];
  unsigned short* lA = smem;
  unsigned short* lB = smem + 8192;
  const int tid = threadIdx.x, wid = tid >> 6, lane = tid & 63;
  const int m0 = blockIdx.x * BM, c0 = blockIdx.y * BCH;
  const int wm = wid >> 2, wn = wid & 3, lr = lane & 15, lg = lane >> 4;

  const unsigned short* bS[3];
#pragma unroll
  for (int q = 0; q < 3; ++q){
    int ci = q * 512 + tid, row = ci >> 3, cp = ci & 7;
    bS[q] = Bm + (size_t)((row >> 6) * 512 + c0 + (row & 63)) * KS + cp * 8;
  }
  unsigned short* bD0 = lB + (size_t)(tid & ~63) * 8;

  f32x4 acc[4][3];
#pragma unroll
  for (int a = 0; a < 4; ++a)
#pragma unroll
    for (int b = 0; b < 3; ++b) acc[a][b] = {0.f, 0.f, 0.f, 0.f};

  for (int kt = 0; kt < NKT; ++kt){
    const bool losec = (kt >= 8);
    const int  ko    = (kt & 7) * 64;
    const int  boff  = (kt & 7) * 64;
    if (kt) __syncthreads();
#pragma unroll
    for (int q = 0; q < 2; ++q){
      int ci = q * 512 + tid, row = ci >> 3, kc = ci & 7;
      const float* src = X + (size_t)(m0 + row) * DIN + ko + kc * 8;
      float4 xa = *(const float4*)src;
      float4 xb = *(const float4*)(src + 4);
      float xs[8] = {xa.x, xa.y, xa.z, xa.w, xb.x, xb.y, xb.z, xb.w};
      unsigned short hs[8];
#pragma unroll
      for (int e = 0; e < 8; ++e){
        unsigned short h = f2bf_rne(xs[e]);
        hs[e] = losec ? f2bf_rne(xs[e] - bf2f(h)) : h;
      }
      uint4 pk;
      pk.x = hs[0] | ((unsigned)hs[1] << 16); pk.y = hs[2] | ((unsigned)hs[3] << 16);
      pk.z = hs[4] | ((unsigned)hs[5] << 16); pk.w = hs[6] | ((unsigned)hs[7] << 16);
      *(uint4*)(lA + row * 64 + ((kc ^ (row & 7)) * 8)) = pk;
    }
#pragma unroll
    for (int q = 0; q < 3; ++q) gld16(bS[q] + boff, bD0 + q * 4096);
    __syncthreads();
#pragma unroll
    for (int kk = 0; kk < 2; ++kk){
      bf16x8 af[4], bfr[3];
#pragma unroll
      for (int mi = 0; mi < 4; ++mi){
        int row = wm * 64 + mi * 16 + lr;
        int ch  = (kk * 4 + lg) ^ (row & 7);
        af[mi] = *(const bf16x8*)(lA + row * 64 + ch * 8);
      }
#pragma unroll
      for (int j = 0; j < 3; ++j){
        int row = j * 64 + wn * 16 + lr;
        int ch  = (kk * 4 + lg) ^ (row & 7);
        bfr[j] = *(const bf16x8*)(lB + row * 64 + ch * 8);
      }
#pragma unroll
      for (int mi = 0; mi < 4; ++mi)
#pragma unroll
        for (int j = 0; j < 3; ++j)
          acc[mi][j] = __builtin_amdgcn_mfma_f32_16x16x32_bf16(af[mi], bfr[j], acc[mi][j], 0, 0, 0);
    }
  }
  gate_epilogue3(acc, m0, c0, wm, wn, lr, lg, bfb, bib, bhb, Fw, Vw);
}

// ============ scan phase A (fallback path only): per-chunk composition ============
__global__ void scan_chunks(const float* __restrict__ Fw, const float* __restrict__ Vw,
                            float2* __restrict__ S){
  int bx = blockIdx.x;
  int chunk = bx >> 2, b = bx & 3;
  int ch4 = threadIdx.x * 4;
  size_t base = ((size_t)(b * T_SEQ + chunk * CHUNK_L)) * DH + ch4;
  float4 Fc = make_float4(1.f, 1.f, 1.f, 1.f);
  float4 Vc = make_float4(0.f, 0.f, 0.f, 0.f);
#pragma unroll 8
  for (int t = 0; t < CHUNK_L; ++t){
    float4 f = *(const float4*)(Fw + base + (size_t)t * DH);
    float4 v = *(const float4*)(Vw + base + (size_t)t * DH);
    Fc.x *= f.x; Fc.y *= f.y; Fc.z *= f.z; Fc.w *= f.w;
    Vc.x = fmaf(f.x, Vc.x, v.x); Vc.y = fmaf(f.y, Vc.y, v.y);
    Vc.z = fmaf(f.z, Vc.z, v.z); Vc.w = fmaf(f.w, Vc.w, v.w);
  }
  float2* s = S + (size_t)chunk * NCH_TOT + b * DH + ch4;
  s[0] = make_float2(Fc.x, Vc.x);
  s[1] = make_float2(Fc.y, Vc.y);
  s[2] = make_float2(Fc.z, Vc.z);
  s[3] = make_float2(Fc.w, Vc.w);
}

// ============ scan phase B: carry; seed = g(h0) ============
__global__ void scan_carry(const float2* __restrict__ S, const float* __restrict__ h0,
                           float* __restrict__ Hs){
  int cg = blockIdx.x * 256 + threadIdx.x;
  float hv = h0[cg];
  float h = (hv >= 0.f) ? (hv + 0.5f) : (1.f / (1.f + expf(-hv)));
  float2 s = S[cg];
#pragma unroll 16
  for (int k = 0; k < NCHUNK; ++k){
    float2 snext = (k + 1 < NCHUNK) ? S[(k + 1) * NCH_TOT + cg] : make_float2(0.f, 0.f);
    Hs[k * NCH_TOT + cg] = h;
    h = fmaf(s.x, h, s.y);
    s = snext;
  }
}

// ============ scan phase C: replay + output (V in d_out, in-place) ============
__global__ void scan_apply(const float* __restrict__ Fw, const float* Vw,
                           const float* __restrict__ Hs, float* out){
  int bx = blockIdx.x;
  int chunk = bx >> 2, b = bx & 3;
  int ch4 = threadIdx.x * 4;
  float4 h = *(const float4*)(Hs + (size_t)chunk * NCH_TOT + b * DH + ch4);
  size_t base = ((size_t)(b * T_SEQ + chunk * CHUNK_L)) * DH + ch4;
#pragma unroll 8
  for (int t = 0; t < CHUNK_L; ++t){
    size_t idx = base + (size_t)t * DH;
    float4 f = *(const float4*)(Fw + idx);
    float4 v = *(const float4*)(Vw + idx);
    h.x = fmaf(f.x, h.x, v.x); h.y = fmaf(f.y, h.y, v.y);
    h.z = fmaf(f.z, h.z, v.z); h.w = fmaf(f.w, h.w, v.w);
    *(float4*)(out + idx) = h;
  }
}

extern "C" void kernel_launch(void* const* d_in, const int* in_sizes, int n_in,
                              void* d_out, int out_size, void* d_ws, size_t ws_size,
                              hipStream_t stream){
  (void)in_sizes; (void)n_in; (void)out_size;
  const float* X  = (const float*)d_in[0];
  const float* h0 = (const float*)d_in[1];
  const float* Wf = (const float*)d_in[2];
  const float* bf = (const float*)d_in[3];
  const float* Wi = (const float*)d_in[4];
  const float* bi = (const float*)d_in[5];
  const float* Wh = (const float*)d_in[6];
  const float* bh = (const float*)d_in[7];

  constexpr size_t XA_B = (size_t)M_TOT * KS * 2;
  constexpr size_t F_B  = (size_t)M_TOT * DH * 4;
  constexpr size_t S_B  = (size_t)NCHUNK * NCH_TOT * 8;
  constexpr size_t H_B  = (size_t)NCHUNK * NCH_TOT * 4;
  constexpr size_t BMB  = (size_t)3 * 512 * KS * 2;
  const bool fast = ws_size >= XA_B + F_B + S_B + H_B + BMB;

  char* ws = (char*)d_ws;
  float* Vw  = (float*)d_out;
  float* out = (float*)d_out;

  if (fast){
    unsigned short* Xa  = (unsigned short*)ws;
    float*          Fw  = (float*)(ws + XA_B);
    float2*         S   = (float2*)(ws + XA_B + F_B);
    float*          Hs  = (float*)(ws + XA_B + F_B + S_B);
    unsigned short* Bmw = (unsigned short*)(ws + XA_B + F_B + S_B + H_B);
    aug_build <<<XB_BLOCKS + BM_BLOCKS, 256, 0, stream>>>(X, Wf, Wi, Wh, Xa, Bmw, 1);
    gemm_fast <<<GRID_WG, 512, 0, stream>>>(Xa, Bmw, bf, bi, bh, Fw, Vw, S);
    scan_carry <<<8, 256, 0, stream>>>(S, h0, Hs);
    scan_apply <<<256, 128, 0, stream>>>(Fw, Vw, Hs, out);
  } else {
    float*          Fw  = (float*)ws;
    float2*         S   = (float2*)(ws + F_B);
    float*          Hs  = (float*)(ws + F_B + S_B);
    unsigned short* Bmw = (unsigned short*)(ws + F_B + S_B + H_B);
    aug_build <<<BM_BLOCKS, 256, 0, stream>>>(X, Wf, Wi, Wh, nullptr, Bmw, 0);
    gemm_slow <<<dim3(M_TOT / BM, DH / BCH), 512, 0, stream>>>(X, Bmw, bf, bi, bh, Fw, Vw);
    scan_chunks<<<256, 128, 0, stream>>>(Fw, Vw, S);
    scan_carry <<<8, 256, 0, stream>>>(S, h0, Hs);
    scan_apply <<<256, 128, 0, stream>>>(Fw, Vw, Hs, out);
  }
}